// Round 6
// baseline (277.341 us; speedup 1.0000x reference)
//
#include <hip/hip_runtime.h>
#include <hip/hip_bf16.h>

typedef __bf16 bf16x8 __attribute__((ext_vector_type(8)));
typedef __bf16 bf16x4 __attribute__((ext_vector_type(4)));
typedef float f32x4 __attribute__((ext_vector_type(4)));

#define D_ 128
#define T_ 2048
#define B_ 4
#define H_ 4
#define NB_ 2

// ---------------------------------------------------------------------------
// Weight prep: fp32 [NB][128][128] (k-major) -> bf16 transposed Wt[j][i][n][k]
// ---------------------------------------------------------------------------
__global__ __launch_bounds__(256) void prep_weights(
    const float* __restrict__ Wq, const float* __restrict__ Wk,
    const float* __restrict__ Wv, const float* __restrict__ Wo,
    const float* __restrict__ W1, const float* __restrict__ W2,
    __bf16* __restrict__ wt)
{
  int tid = blockIdx.x * 256 + threadIdx.x;   // < 6*NB*128*128
  int j   = tid >> 15;
  int rem = tid & 32767;
  int i   = rem >> 14;
  int n   = (rem >> 7) & 127;
  int kk  = rem & 127;
  const float* srcs[6] = {Wq, Wk, Wv, Wo, W1, W2};
  wt[tid] = (__bf16)srcs[j][i * 16384 + kk * 128 + n];
}

// ---------------------------------------------------------------------------
// h0 = bf16(inputs + pos_encoding). One wave per row (2 cols/lane).
// ---------------------------------------------------------------------------
__global__ __launch_bounds__(256) void posadd(
    const float* __restrict__ x, __bf16* __restrict__ out)
{
  int w = threadIdx.x >> 6, lane = threadIdx.x & 63;
  int row = blockIdx.x * 4 + w;
  int t = row & (T_ - 1);
  #pragma unroll
  for (int e = 0; e < 2; e++) {
    int c = lane * 2 + e;
    float arg = (float)t * exp2f(-0.20762050593045952f * (float)c);
    float pe = (c & 1) ? cosf(arg) : sinf(arg);
    out[row * D_ + c] = (__bf16)(x[row * D_ + c] + pe);
  }
}

// ---------------------------------------------------------------------------
// Fused LN + QKV. One wave per 16 rows. LN is computed in-register from the
// A-fragments (frag row = lane&15; row-reduce = shfl_xor 16 + 32), then
// Q, K, V GEMMs reuse the normalized fragments.
// mfma_f32_16x16x32_bf16 layouts:
//   A: lane holds A[lane%16][8*(lane/16)+e]   (+32 per k-step)
//   B: lane holds B[8*(lane/16)+e][lane%16]
//   C/D: lane holds D[(lane/16)*4+r][lane%16]
// ---------------------------------------------------------------------------
__global__ __launch_bounds__(64) void lnqkv(
    const __bf16* __restrict__ hsrc, const __bf16* __restrict__ wtq,
    const __bf16* __restrict__ wtk, const __bf16* __restrict__ wtv,
    const float* __restrict__ bq, const float* __restrict__ bk,
    const float* __restrict__ bv, const float* __restrict__ g,
    const float* __restrict__ beta,
    __bf16* __restrict__ qo, __bf16* __restrict__ ko, __bf16* __restrict__ vo)
{
  int lane = threadIdx.x;
  int m0 = blockIdx.x * 16;
  int lr = lane & 15, kg = lane >> 4;

  const __bf16* arow = hsrc + (size_t)(m0 + lr) * D_ + kg * 8;
  bf16x8 araw[4];
  #pragma unroll
  for (int ks = 0; ks < 4; ks++) araw[ks] = *(const bf16x8*)(arow + ks * 32);

  // LN stats for row lr (each lane holds 32 of its 128 cols)
  float s = 0.f, s2 = 0.f;
  #pragma unroll
  for (int ks = 0; ks < 4; ks++)
    #pragma unroll
    for (int e = 0; e < 8; e++) {
      float x = (float)araw[ks][e];
      s += x; s2 += x * x;
    }
  s += __shfl_xor(s, 16, 64);  s2 += __shfl_xor(s2, 16, 64);
  s += __shfl_xor(s, 32, 64);  s2 += __shfl_xor(s2, 32, 64);
  float mu = s * (1.f / D_);
  float var = s2 * (1.f / D_) - mu * mu;
  float rstd = rsqrtf(var + 1e-3f);

  bf16x8 af[4];
  #pragma unroll
  for (int ks = 0; ks < 4; ks++) {
    int c0 = ks * 32 + kg * 8;
    float4 g0 = *(const float4*)(g + c0), g1 = *(const float4*)(g + c0 + 4);
    float4 q0 = *(const float4*)(beta + c0), q1 = *(const float4*)(beta + c0 + 4);
    const float* gp[2] = {&g0.x, &g1.x};
    const float* bp[2] = {&q0.x, &q1.x};
    #pragma unroll
    for (int e = 0; e < 8; e++)
      af[ks][e] = (__bf16)(((float)araw[ks][e] - mu) * rstd * gp[e >> 2][e & 3] + bp[e >> 2][e & 3]);
  }

  // ---- Q ----
  {
    f32x4 acc[8];
    #pragma unroll
    for (int nt = 0; nt < 8; nt++) acc[nt] = (f32x4){0.f, 0.f, 0.f, 0.f};
    #pragma unroll
    for (int nt = 0; nt < 8; nt++) {
      const __bf16* wrow = wtq + (size_t)(nt * 16 + lr) * D_ + kg * 8;
      #pragma unroll
      for (int ks = 0; ks < 4; ks++)
        acc[nt] = __builtin_amdgcn_mfma_f32_16x16x32_bf16(af[ks], *(const bf16x8*)(wrow + ks * 32), acc[nt], 0, 0, 0);
    }
    #pragma unroll
    for (int nt = 0; nt < 8; nt++) {
      float bcol = bq[nt * 16 + lr];
      #pragma unroll
      for (int r = 0; r < 4; r++)
        qo[(size_t)(m0 + kg * 4 + r) * D_ + nt * 16 + lr] = (__bf16)(acc[nt][r] + bcol);
    }
  }
  // ---- K ----
  {
    f32x4 acc[8];
    #pragma unroll
    for (int nt = 0; nt < 8; nt++) acc[nt] = (f32x4){0.f, 0.f, 0.f, 0.f};
    #pragma unroll
    for (int nt = 0; nt < 8; nt++) {
      const __bf16* wrow = wtk + (size_t)(nt * 16 + lr) * D_ + kg * 8;
      #pragma unroll
      for (int ks = 0; ks < 4; ks++)
        acc[nt] = __builtin_amdgcn_mfma_f32_16x16x32_bf16(af[ks], *(const bf16x8*)(wrow + ks * 32), acc[nt], 0, 0, 0);
    }
    #pragma unroll
    for (int nt = 0; nt < 8; nt++) {
      float bcol = bk[nt * 16 + lr];
      #pragma unroll
      for (int r = 0; r < 4; r++)
        ko[(size_t)(m0 + kg * 4 + r) * D_ + nt * 16 + lr] = (__bf16)(acc[nt][r] + bcol);
    }
  }
  // ---- V (transposed store: vT[b][h][dk][t]) ----
  {
    f32x4 acc[8];
    #pragma unroll
    for (int nt = 0; nt < 8; nt++) acc[nt] = (f32x4){0.f, 0.f, 0.f, 0.f};
    #pragma unroll
    for (int nt = 0; nt < 8; nt++) {
      const __bf16* wrow = wtv + (size_t)(nt * 16 + lr) * D_ + kg * 8;
      #pragma unroll
      for (int ks = 0; ks < 4; ks++)
        acc[nt] = __builtin_amdgcn_mfma_f32_16x16x32_bf16(af[ks], *(const bf16x8*)(wrow + ks * 32), acc[nt], 0, 0, 0);
    }
    #pragma unroll
    for (int nt = 0; nt < 8; nt++) {
      float bcol = bv[nt * 16 + lr];
      #pragma unroll
      for (int r = 0; r < 4; r++) {
        int row = m0 + kg * 4 + r, col = nt * 16 + lr;
        int b = row >> 11, t = row & (T_ - 1);
        int h = col >> 5, dk = col & 31;
        vo[((size_t)(b * H_ + h) * 32 + dk) * T_ + t] = (__bf16)(acc[nt][r] + bcol);
      }
    }
  }
}

// ---------------------------------------------------------------------------
// Flash attention with software-pipelined K/V prefetch. Block = 4 waves =
// 2 q-tiles x 2 KV-halves. S^T = mfma(K, Q): lane owns q = lane&15, 16 keys
// in regs -> row-reduce = in-reg max + 2 shuffles. exp2-domain softmax
// (scale*log2e folded into Q). P staged via XOR-swizzled per-wave LDS.
// ---------------------------------------------------------------------------
__global__ __launch_bounds__(256) void attn3(
    const __bf16* __restrict__ q, const __bf16* __restrict__ k,
    const __bf16* __restrict__ vT, __bf16* __restrict__ ctx)
{
  __shared__ __attribute__((aligned(16))) __bf16 pbuf[4][16][64];
  __shared__ float mbuf[2][64][10];

  int w = threadIdx.x >> 6, lane = threadIdx.x & 63;
  int pair = w >> 1, half = w & 1;
  int tile = blockIdx.x * 2 + pair;
  int qt = tile & 127, bh = tile >> 7;
  int b = bh >> 2, h = bh & 3;
  int lr = lane & 15, kg = lane >> 4;
  int swz = (lr & 7) << 3;

  bf16x8 qraw = *(const bf16x8*)(q + (size_t)(b * T_ + qt * 16 + lr) * D_ + h * 32 + kg * 8);
  bf16x8 qf;
  const float qscale = 0.17677669529663687f * 1.4426950408889634f;  // 1/sqrt(32)*log2e
  #pragma unroll
  for (int e = 0; e < 8; e++) qf[e] = (__bf16)((float)qraw[e] * qscale);

  const __bf16* kbase = k + (size_t)b * T_ * D_ + h * 32 + kg * 8;
  const __bf16* vbase = vT + (size_t)((b * H_ + h) * 32) * T_;

  float m = -1e30f, l = 0.f;
  f32x4 acc0 = {0, 0, 0, 0}, acc1 = {0, 0, 0, 0};
  const f32x4 zero = {0, 0, 0, 0};
  char* pb_base = (char*)&pbuf[w][0][0] + lr * 128;

  int k0 = half * 1024;
  bf16x8 kf[4];
  #pragma unroll
  for (int kb = 0; kb < 4; kb++)
    kf[kb] = *(const bf16x8*)(kbase + (size_t)(k0 + kb * 16 + lr) * D_);

  for (int it = 0; it < 16; it++) {
    // prefetch V for this tile (independent of S) — hides under QK+softmax
    const __bf16* vrow = vbase + k0 + kg * 8;
    bf16x8 v00 = *(const bf16x8*)(vrow + (size_t)lr * T_);
    bf16x8 v01 = *(const bf16x8*)(vrow + (size_t)lr * T_ + 32);
    bf16x8 v10 = *(const bf16x8*)(vrow + (size_t)(16 + lr) * T_);
    bf16x8 v11 = *(const bf16x8*)(vrow + (size_t)(16 + lr) * T_ + 32);

    f32x4 s[4];
    #pragma unroll
    for (int kb = 0; kb < 4; kb++)
      s[kb] = __builtin_amdgcn_mfma_f32_16x16x32_bf16(kf[kb], qf, zero, 0, 0, 0);

    // prefetch next K tile — hides under softmax+PV
    bf16x8 kn[4];
    if (it < 15) {
      #pragma unroll
      for (int kb = 0; kb < 4; kb++)
        kn[kb] = *(const bf16x8*)(kbase + (size_t)(k0 + 64 + kb * 16 + lr) * D_);
    }

    float tm = s[0][0];
    #pragma unroll
    for (int kb = 0; kb < 4; kb++)
      #pragma unroll
      for (int r = 0; r < 4; r++) tm = fmaxf(tm, s[kb][r]);
    tm = fmaxf(tm, __shfl_xor(tm, 16, 64));
    tm = fmaxf(tm, __shfl_xor(tm, 32, 64));
    float mnew = fmaxf(m, tm);
    float corr = exp2f(m - mnew);
    m = mnew;
    float rs = 0.f;
    #pragma unroll
    for (int kb = 0; kb < 4; kb++) {
      bf16x4 pk;
      #pragma unroll
      for (int r = 0; r < 4; r++) {
        float p = exp2f(s[kb][r] - mnew);
        rs += p;
        pk[r] = (__bf16)p;
      }
      *(bf16x4*)(pb_base + (((kb * 16 + kg * 4) ^ swz) * 2)) = pk;
    }
    rs += __shfl_xor(rs, 16, 64);
    rs += __shfl_xor(rs, 32, 64);
    l = l * corr + rs;
    #pragma unroll
    for (int r = 0; r < 4; r++) { acc0[r] *= corr; acc1[r] *= corr; }

    {
      bf16x8 pf0 = *(const bf16x8*)(pb_base + (((0 * 32 + kg * 8) ^ swz) * 2));
      bf16x8 pf1 = *(const bf16x8*)(pb_base + (((1 * 32 + kg * 8) ^ swz) * 2));
      acc0 = __builtin_amdgcn_mfma_f32_16x16x32_bf16(v00, pf0, acc0, 0, 0, 0);
      acc1 = __builtin_amdgcn_mfma_f32_16x16x32_bf16(v10, pf0, acc1, 0, 0, 0);
      acc0 = __builtin_amdgcn_mfma_f32_16x16x32_bf16(v01, pf1, acc0, 0, 0, 0);
      acc1 = __builtin_amdgcn_mfma_f32_16x16x32_bf16(v11, pf1, acc1, 0, 0, 0);
    }
    #pragma unroll
    for (int kb = 0; kb < 4; kb++) kf[kb] = kn[kb];
    k0 += 64;
  }

  if (half == 1) {
    float* mb = &mbuf[pair][lane][0];
    #pragma unroll
    for (int r = 0; r < 4; r++) { mb[r] = acc0[r]; mb[4 + r] = acc1[r]; }
    mb[8] = m; mb[9] = l;
  }
  __syncthreads();
  if (half == 0) {
    const float* mb = &mbuf[pair][lane][0];
    float m2 = mb[8], l2 = mb[9];
    float mm = fmaxf(m, m2);
    float c1 = exp2f(m - mm), c2 = exp2f(m2 - mm);
    float inv = 1.f / (l * c1 + l2 * c2);
    __bf16* crow = ctx + (size_t)(b * T_ + qt * 16 + lr) * D_ + h * 32 + kg * 4;
    #pragma unroll
    for (int r = 0; r < 4; r++) {
      crow[r]      = (__bf16)((acc0[r] * c1 + mb[r] * c2) * inv);
      crow[16 + r] = (__bf16)((acc1[r] * c1 + mb[4 + r] * c2) * inv);
    }
  }
}

// ---------------------------------------------------------------------------
// Fused Wo + LN + FFN (+ final LN): one wave per 16 rows, single-wave block
// (no barriers needed; per-wave in-order DS ops). Two LDS transposes via
// the XOR-swizzled tbuf pattern (validated in round-1 ffn_fused).
// ---------------------------------------------------------------------------
template <int LAST>
__global__ __launch_bounds__(64) void wo_ffn(
    const __bf16* __restrict__ ctxb, const __bf16* __restrict__ wto,
    const float* __restrict__ bo, const float* __restrict__ g1,
    const float* __restrict__ bt1, const __bf16* __restrict__ wt1,
    const float* __restrict__ b1, const __bf16* __restrict__ wt2,
    const float* __restrict__ b2, const float* __restrict__ g2,
    const float* __restrict__ bt2, __bf16* __restrict__ outb,
    float* __restrict__ outf)
{
  __shared__ __attribute__((aligned(16))) __bf16 tbuf[16][128];
  int lane = threadIdx.x;
  int m0 = blockIdx.x * 16;
  int lr = lane & 15, kg = lane >> 4;

  const __bf16* arow = ctxb + (size_t)(m0 + lr) * D_ + kg * 8;
  bf16x8 af[4];
  #pragma unroll
  for (int ks = 0; ks < 4; ks++) af[ks] = *(const bf16x8*)(arow + ks * 32);

  // ---- Wo GEMM ----
  f32x4 acc[8];
  #pragma unroll
  for (int nt = 0; nt < 8; nt++) acc[nt] = (f32x4){0.f, 0.f, 0.f, 0.f};
  #pragma unroll
  for (int nt = 0; nt < 8; nt++) {
    const __bf16* wrow = wto + (size_t)(nt * 16 + lr) * D_ + kg * 8;
    #pragma unroll
    for (int ks = 0; ks < 4; ks++)
      acc[nt] = __builtin_amdgcn_mfma_f32_16x16x32_bf16(af[ks], *(const bf16x8*)(wrow + ks * 32), acc[nt], 0, 0, 0);
  }

  // ---- +bo, LN(g1,bt1); keep hres (post-LN) in C-layout; transpose to LDS ----
  float xv[8][4];
  float s[4] = {0, 0, 0, 0}, s2[4] = {0, 0, 0, 0};
  #pragma unroll
  for (int nt = 0; nt < 8; nt++) {
    float bcol = bo[nt * 16 + lr];
    #pragma unroll
    for (int r = 0; r < 4; r++) {
      float y = acc[nt][r] + bcol;
      xv[nt][r] = y; s[r] += y; s2[r] += y * y;
    }
  }
  #pragma unroll
  for (int r = 0; r < 4; r++)
    for (int mk = 1; mk < 16; mk <<= 1) {
      s[r] += __shfl_xor(s[r], mk, 64);
      s2[r] += __shfl_xor(s2[r], mk, 64);
    }
  float hres[8][4];
  #pragma unroll
  for (int nt = 0; nt < 8; nt++) {
    float gc = g1[nt * 16 + lr], bc = bt1[nt * 16 + lr];
    #pragma unroll
    for (int r = 0; r < 4; r++) {
      float mu = s[r] * (1.f / D_);
      float var = s2[r] * (1.f / D_) - mu * mu;
      float rstd = rsqrtf(var + 1e-3f);
      float y = (xv[nt][r] - mu) * rstd * gc + bc;
      hres[nt][r] = y;
      int row = kg * 4 + r, col = nt * 16 + lr;
      ((__bf16*)tbuf)[row * 128 + (col ^ ((row & 7) << 3))] = (__bf16)y;
    }
  }

  // ---- W1 + ReLU ----
  int swz = (lr & 7) << 3;
  bf16x8 a2[4];
  #pragma unroll
  for (int ks = 0; ks < 4; ks++)
    a2[ks] = *(const bf16x8*)((const __bf16*)tbuf + lr * 128 + ((ks * 32 + kg * 8) ^ swz));
  f32x4 acc2[8];
  #pragma unroll
  for (int nt = 0; nt < 8; nt++) acc2[nt] = (f32x4){0.f, 0.f, 0.f, 0.f};
  #pragma unroll
  for (int nt = 0; nt < 8; nt++) {
    const __bf16* wrow = wt1 + (size_t)(nt * 16 + lr) * D_ + kg * 8;
    #pragma unroll
    for (int ks = 0; ks < 4; ks++)
      acc2[nt] = __builtin_amdgcn_mfma_f32_16x16x32_bf16(a2[ks], *(const bf16x8*)(wrow + ks * 32), acc2[nt], 0, 0, 0);
  }
  // relu -> transpose (per-wave in-order DS: reads above complete before writes)
  #pragma unroll
  for (int nt = 0; nt < 8; nt++) {
    float bcol = b1[nt * 16 + lr];
    #pragma unroll
    for (int r = 0; r < 4; r++) {
      int row = kg * 4 + r, col = nt * 16 + lr;
      ((__bf16*)tbuf)[row * 128 + (col ^ ((row & 7) << 3))] =
          (__bf16)fmaxf(acc2[nt][r] + bcol, 0.f);
    }
  }

  // ---- W2 + residual ----
  bf16x8 a3[4];
  #pragma unroll
  for (int ks = 0; ks < 4; ks++)
    a3[ks] = *(const bf16x8*)((const __bf16*)tbuf + lr * 128 + ((ks * 32 + kg * 8) ^ swz));
  f32x4 acc3[8];
  #pragma unroll
  for (int nt = 0; nt < 8; nt++) acc3[nt] = (f32x4){0.f, 0.f, 0.f, 0.f};
  #pragma unroll
  for (int nt = 0; nt < 8; nt++) {
    const __bf16* wrow = wt2 + (size_t)(nt * 16 + lr) * D_ + kg * 8;
    #pragma unroll
    for (int ks = 0; ks < 4; ks++)
      acc3[nt] = __builtin_amdgcn_mfma_f32_16x16x32_bf16(a3[ks], *(const bf16x8*)(wrow + ks * 32), acc3[nt], 0, 0, 0);
  }

  if constexpr (LAST) {
    // h2 = hres + t1@W2 + b2, then final LN(g2,bt2) -> fp32 out
    float yv[8][4];
    float t[4] = {0, 0, 0, 0}, t2[4] = {0, 0, 0, 0};
    #pragma unroll
    for (int nt = 0; nt < 8; nt++) {
      float bcol = b2[nt * 16 + lr];
      #pragma unroll
      for (int r = 0; r < 4; r++) {
        float y = acc3[nt][r] + bcol + hres[nt][r];
        yv[nt][r] = y; t[r] += y; t2[r] += y * y;
      }
    }
    #pragma unroll
    for (int r = 0; r < 4; r++)
      for (int mk = 1; mk < 16; mk <<= 1) {
        t[r] += __shfl_xor(t[r], mk, 64);
        t2[r] += __shfl_xor(t2[r], mk, 64);
      }
    #pragma unroll
    for (int nt = 0; nt < 8; nt++) {
      float gc = g2[nt * 16 + lr], bc = bt2[nt * 16 + lr];
      #pragma unroll
      for (int r = 0; r < 4; r++) {
        float mu = t[r] * (1.f / D_);
        float var = t2[r] * (1.f / D_) - mu * mu;
        float rstd = rsqrtf(var + 1e-3f);
        outf[(size_t)(m0 + kg * 4 + r) * D_ + nt * 16 + lr] =
            (yv[nt][r] - mu) * rstd * gc + bc;
      }
    }
  } else {
    #pragma unroll
    for (int nt = 0; nt < 8; nt++) {
      float bcol = b2[nt * 16 + lr];
      #pragma unroll
      for (int r = 0; r < 4; r++)
        outb[(size_t)(m0 + kg * 4 + r) * D_ + nt * 16 + lr] =
            (__bf16)(acc3[nt][r] + bcol + hres[nt][r]);
    }
  }
}

// ---------------------------------------------------------------------------
extern "C" void kernel_launch(void* const* d_in, const int* in_sizes, int n_in,
                              void* d_out, int out_size, void* d_ws, size_t ws_size,
                              hipStream_t stream)
{
  const float* inputs = (const float*)d_in[0];
  const float* Wq = (const float*)d_in[1];
  const float* bq = (const float*)d_in[2];
  const float* Wk = (const float*)d_in[3];
  const float* bk = (const float*)d_in[4];
  const float* Wv = (const float*)d_in[5];
  const float* bv = (const float*)d_in[6];
  const float* Wo = (const float*)d_in[7];
  const float* bo = (const float*)d_in[8];
  const float* W1 = (const float*)d_in[9];
  const float* b1 = (const float*)d_in[10];
  const float* W2 = (const float*)d_in[11];
  const float* b2 = (const float*)d_in[12];
  const float* ln_g = (const float*)d_in[13];
  const float* ln_b = (const float*)d_in[14];
  float* out = (float*)d_out;

  char* ws = (char*)d_ws;
  size_t off = 0;
  auto alloc = [&](size_t bytes) {
    void* p = ws + off;
    off = (off + bytes + 255) & ~(size_t)255;
    return p;
  };
  const size_t ACT = (size_t)8192 * 128 * sizeof(__bf16);  // 2 MB
  __bf16* wt   = (__bf16*)alloc((size_t)6 * NB_ * 128 * 128 * sizeof(__bf16));
  __bf16* hbuf = (__bf16*)alloc(ACT);   // h0 / h1 (pre-LN layer input)
  __bf16* qb   = (__bf16*)alloc(ACT);
  __bf16* kb   = (__bf16*)alloc(ACT);
  __bf16* vb   = (__bf16*)alloc(ACT);
  __bf16* ctxb = (__bf16*)alloc(ACT);

  prep_weights<<<768, 256, 0, stream>>>(Wq, Wk, Wv, Wo, W1, W2, wt);
  posadd<<<2048, 256, 0, stream>>>(inputs, hbuf);

  for (int i = 0; i < NB_; i++) {
    const __bf16* wtq = wt + (size_t)(0 * NB_ + i) * 16384;
    const __bf16* wtk = wt + (size_t)(1 * NB_ + i) * 16384;
    const __bf16* wtv = wt + (size_t)(2 * NB_ + i) * 16384;
    const __bf16* wto = wt + (size_t)(3 * NB_ + i) * 16384;
    const __bf16* wt1 = wt + (size_t)(4 * NB_ + i) * 16384;
    const __bf16* wt2 = wt + (size_t)(5 * NB_ + i) * 16384;

    lnqkv<<<512, 64, 0, stream>>>(hbuf, wtq, wtk, wtv,
                                  bq + i * 128, bk + i * 128, bv + i * 128,
                                  ln_g + (size_t)(2 * i) * 128, ln_b + (size_t)(2 * i) * 128,
                                  qb, kb, vb);
    attn3<<<1024, 256, 0, stream>>>(qb, kb, vb, ctxb);
    if (i == 0) {
      wo_ffn<0><<<512, 64, 0, stream>>>(ctxb, wto, bo + i * 128,
                                        ln_g + 1 * 128, ln_b + 1 * 128,
                                        wt1, b1 + i * 128, wt2, b2 + i * 128,
                                        nullptr, nullptr, hbuf, nullptr);
    } else {
      wo_ffn<1><<<512, 64, 0, stream>>>(ctxb, wto, bo + i * 128,
                                        ln_g + 3 * 128, ln_b + 3 * 128,
                                        wt1, b1 + i * 128, wt2, b2 + i * 128,
                                        ln_g + 3 * 128, ln_b + 3 * 128,
                                        nullptr, out);
    }
  }
}

// Round 7
// 255.454 us; speedup vs baseline: 1.0857x; 1.0857x over previous
//
#include <hip/hip_runtime.h>
#include <hip/hip_bf16.h>

typedef __bf16 bf16x8 __attribute__((ext_vector_type(8)));
typedef __bf16 bf16x4 __attribute__((ext_vector_type(4)));
typedef float f32x4 __attribute__((ext_vector_type(4)));

#define D_ 128
#define T_ 2048
#define B_ 4
#define H_ 4
#define NB_ 2

// ---------------------------------------------------------------------------
// Weight prep: fp32 [NB][128][128] (k-major) -> bf16 transposed Wt[j][i][n][k]
// ---------------------------------------------------------------------------
__global__ __launch_bounds__(256) void prep_weights(
    const float* __restrict__ Wq, const float* __restrict__ Wk,
    const float* __restrict__ Wv, const float* __restrict__ Wo,
    const float* __restrict__ W1, const float* __restrict__ W2,
    __bf16* __restrict__ wt)
{
  int tid = blockIdx.x * 256 + threadIdx.x;   // < 6*NB*128*128
  int j   = tid >> 15;
  int rem = tid & 32767;
  int i   = rem >> 14;
  int n   = (rem >> 7) & 127;
  int kk  = rem & 127;
  const float* srcs[6] = {Wq, Wk, Wv, Wo, W1, W2};
  wt[tid] = (__bf16)srcs[j][i * 16384 + kk * 128 + n];
}

// ---------------------------------------------------------------------------
// h0 = bf16(inputs + pos_encoding). One wave per row (2 cols/lane).
// ---------------------------------------------------------------------------
__global__ __launch_bounds__(256) void posadd(
    const float* __restrict__ x, __bf16* __restrict__ out)
{
  int w = threadIdx.x >> 6, lane = threadIdx.x & 63;
  int row = blockIdx.x * 4 + w;
  int t = row & (T_ - 1);
  #pragma unroll
  for (int e = 0; e < 2; e++) {
    int c = lane * 2 + e;
    float arg = (float)t * exp2f(-0.20762050593045952f * (float)c);
    float pe = (c & 1) ? cosf(arg) : sinf(arg);
    out[row * D_ + c] = (__bf16)(x[row * D_ + c] + pe);
  }
}

// ---------------------------------------------------------------------------
// Fused LN + QKV, N-split: 4 waves/block, wave w computes cols [w*32, w*32+32)
// of Q, K, V for the block's 16 rows. LN in-register from A-frags (row = lr;
// reduce over kg via shfl_xor 16+32). 2048 waves total.
// mfma_f32_16x16x32_bf16 layouts:
//   A: lane holds A[lane%16][8*(lane/16)+e]   (+32 per k-step)
//   B: lane holds B[8*(lane/16)+e][lane%16]
//   C/D: lane holds D[(lane/16)*4+r][lane%16]
// ---------------------------------------------------------------------------
__global__ __launch_bounds__(256) void lnqkv(
    const __bf16* __restrict__ hsrc, const __bf16* __restrict__ wtq,
    const __bf16* __restrict__ wtk, const __bf16* __restrict__ wtv,
    const float* __restrict__ bq, const float* __restrict__ bk,
    const float* __restrict__ bv, const float* __restrict__ g,
    const float* __restrict__ beta,
    __bf16* __restrict__ qo, __bf16* __restrict__ ko, __bf16* __restrict__ vo)
{
  int w = threadIdx.x >> 6, lane = threadIdx.x & 63;
  int m0 = blockIdx.x * 16;
  int lr = lane & 15, kg = lane >> 4;

  const __bf16* arow = hsrc + (size_t)(m0 + lr) * D_ + kg * 8;
  bf16x8 araw[4];
  #pragma unroll
  for (int ks = 0; ks < 4; ks++) araw[ks] = *(const bf16x8*)(arow + ks * 32);

  // LN stats for row lr
  float s = 0.f, s2 = 0.f;
  #pragma unroll
  for (int ks = 0; ks < 4; ks++)
    #pragma unroll
    for (int e = 0; e < 8; e++) {
      float x = (float)araw[ks][e];
      s += x; s2 += x * x;
    }
  s += __shfl_xor(s, 16, 64);  s2 += __shfl_xor(s2, 16, 64);
  s += __shfl_xor(s, 32, 64);  s2 += __shfl_xor(s2, 32, 64);
  float mu = s * (1.f / D_);
  float var = s2 * (1.f / D_) - mu * mu;
  float rstd = rsqrtf(var + 1e-3f);

  bf16x8 af[4];
  #pragma unroll
  for (int ks = 0; ks < 4; ks++) {
    int c0 = ks * 32 + kg * 8;
    float4 g0 = *(const float4*)(g + c0), g1 = *(const float4*)(g + c0 + 4);
    float4 q0 = *(const float4*)(beta + c0), q1 = *(const float4*)(beta + c0 + 4);
    const float* gp[2] = {&g0.x, &g1.x};
    const float* bp[2] = {&q0.x, &q1.x};
    #pragma unroll
    for (int e = 0; e < 8; e++)
      af[ks][e] = (__bf16)(((float)araw[ks][e] - mu) * rstd * gp[e >> 2][e & 3] + bp[e >> 2][e & 3]);
  }

  #pragma unroll
  for (int i = 0; i < 2; i++) {
    int nt = w * 2 + i;
    const __bf16* wq = wtq + (size_t)(nt * 16 + lr) * D_ + kg * 8;
    const __bf16* wk = wtk + (size_t)(nt * 16 + lr) * D_ + kg * 8;
    const __bf16* wv = wtv + (size_t)(nt * 16 + lr) * D_ + kg * 8;
    f32x4 aq = {0, 0, 0, 0}, ak = {0, 0, 0, 0}, av = {0, 0, 0, 0};
    #pragma unroll
    for (int ks = 0; ks < 4; ks++) {
      aq = __builtin_amdgcn_mfma_f32_16x16x32_bf16(af[ks], *(const bf16x8*)(wq + ks * 32), aq, 0, 0, 0);
      ak = __builtin_amdgcn_mfma_f32_16x16x32_bf16(af[ks], *(const bf16x8*)(wk + ks * 32), ak, 0, 0, 0);
      av = __builtin_amdgcn_mfma_f32_16x16x32_bf16(af[ks], *(const bf16x8*)(wv + ks * 32), av, 0, 0, 0);
    }
    int col = nt * 16 + lr;
    float bqc = bq[col], bkc = bk[col], bvc = bv[col];
    int hh = col >> 5, dk = col & 31;
    #pragma unroll
    for (int r = 0; r < 4; r++) {
      int row = m0 + kg * 4 + r;
      qo[(size_t)row * D_ + col] = (__bf16)(aq[r] + bqc);
      ko[(size_t)row * D_ + col] = (__bf16)(ak[r] + bkc);
      int bb = row >> 11, t = row & (T_ - 1);
      vo[((size_t)(bb * H_ + hh) * 32 + dk) * T_ + t] = (__bf16)(av[r] + bvc);
    }
  }
}

// ---------------------------------------------------------------------------
// Flash attention v4: fixed-max softmax (no online max tracking — scores are
// O(1) after LN so exp2(s-24) can't overflow/underflow; acc/l division makes
// it mathematically identical), 4-way KV split (4 waves/block, one q-tile),
// XCD-swizzled grid (bh = blockIdx&15 keeps each (b,h)'s K/V on one XCD's L2).
// S^T = mfma(K, Q): lane owns q = lane&15, 16 keys in regs; no cross-lane ops
// in the loop except the P LDS staging. l reduced once at the end.
// ---------------------------------------------------------------------------
__global__ __launch_bounds__(256) void attn4(
    const __bf16* __restrict__ q, const __bf16* __restrict__ k,
    const __bf16* __restrict__ vT, __bf16* __restrict__ ctx)
{
  __shared__ __attribute__((aligned(16))) __bf16 pbuf[4][16][64];
  __shared__ float mbuf[4][64][9];

  int w = threadIdx.x >> 6, lane = threadIdx.x & 63;
  int bh = blockIdx.x & 15, qt = blockIdx.x >> 4;
  int b = bh >> 2, h = bh & 3;
  int lr = lane & 15, kg = lane >> 4;
  int swz = (lr & 7) << 3;

  bf16x8 qraw = *(const bf16x8*)(q + (size_t)(b * T_ + qt * 16 + lr) * D_ + h * 32 + kg * 8);
  bf16x8 qf;
  const float qscale = 0.17677669529663687f * 1.4426950408889634f;  // 1/sqrt(32)*log2e
  #pragma unroll
  for (int e = 0; e < 8; e++) qf[e] = (__bf16)((float)qraw[e] * qscale);

  const __bf16* kbase = k + (size_t)b * T_ * D_ + h * 32 + kg * 8;
  const __bf16* vbase = vT + (size_t)((b * H_ + h) * 32) * T_;

  float l = 0.f;
  f32x4 acc0 = {0, 0, 0, 0}, acc1 = {0, 0, 0, 0};
  const f32x4 zero = {0, 0, 0, 0};
  char* pb_base = (char*)&pbuf[w][0][0] + lr * 128;

  int k0 = w * 512;
  bf16x8 kf[4];
  #pragma unroll
  for (int kb = 0; kb < 4; kb++)
    kf[kb] = *(const bf16x8*)(kbase + (size_t)(k0 + kb * 16 + lr) * D_);

  for (int it = 0; it < 8; it++) {
    // V prefetch for this tile (independent of S)
    const __bf16* vrow = vbase + k0 + kg * 8;
    bf16x8 v00 = *(const bf16x8*)(vrow + (size_t)lr * T_);
    bf16x8 v01 = *(const bf16x8*)(vrow + (size_t)lr * T_ + 32);
    bf16x8 v10 = *(const bf16x8*)(vrow + (size_t)(16 + lr) * T_);
    bf16x8 v11 = *(const bf16x8*)(vrow + (size_t)(16 + lr) * T_ + 32);

    __builtin_amdgcn_s_setprio(1);
    f32x4 s[4];
    #pragma unroll
    for (int kb = 0; kb < 4; kb++)
      s[kb] = __builtin_amdgcn_mfma_f32_16x16x32_bf16(kf[kb], qf, zero, 0, 0, 0);
    __builtin_amdgcn_s_setprio(0);

    // next K tile prefetch — hides under softmax+PV
    bf16x8 kn[4];
    if (it < 7) {
      #pragma unroll
      for (int kb = 0; kb < 4; kb++)
        kn[kb] = *(const bf16x8*)(kbase + (size_t)(k0 + 64 + kb * 16 + lr) * D_);
    }

    // fixed-max softmax: p = exp2(s - 24); no cross-lane reduce in-loop
    float rs = 0.f;
    #pragma unroll
    for (int kb = 0; kb < 4; kb++) {
      bf16x4 pk;
      #pragma unroll
      for (int r = 0; r < 4; r++) {
        float p = exp2f(s[kb][r] - 24.f);
        rs += p;
        pk[r] = (__bf16)p;
      }
      *(bf16x4*)(pb_base + (((kb * 16 + kg * 4) ^ swz) * 2)) = pk;
    }
    l += rs;

    bf16x8 pf0 = *(const bf16x8*)(pb_base + (((kg * 8) ^ swz) * 2));
    bf16x8 pf1 = *(const bf16x8*)(pb_base + (((32 + kg * 8) ^ swz) * 2));
    __builtin_amdgcn_s_setprio(1);
    acc0 = __builtin_amdgcn_mfma_f32_16x16x32_bf16(v00, pf0, acc0, 0, 0, 0);
    acc1 = __builtin_amdgcn_mfma_f32_16x16x32_bf16(v10, pf0, acc1, 0, 0, 0);
    acc0 = __builtin_amdgcn_mfma_f32_16x16x32_bf16(v01, pf1, acc0, 0, 0, 0);
    acc1 = __builtin_amdgcn_mfma_f32_16x16x32_bf16(v11, pf1, acc1, 0, 0, 0);
    __builtin_amdgcn_s_setprio(0);

    #pragma unroll
    for (int kb = 0; kb < 4; kb++) kf[kb] = kn[kb];
    k0 += 64;
  }

  // finish per-q-row l: sum across the 4 kg groups
  l += __shfl_xor(l, 16, 64);
  l += __shfl_xor(l, 32, 64);

  float* mb = &mbuf[w][lane][0];
  #pragma unroll
  for (int r = 0; r < 4; r++) { mb[r] = acc0[r]; mb[4 + r] = acc1[r]; }
  mb[8] = l;
  __syncthreads();
  if (w == 0) {
    #pragma unroll
    for (int w2 = 1; w2 < 4; w2++) {
      const float* m2 = &mbuf[w2][lane][0];
      #pragma unroll
      for (int r = 0; r < 4; r++) { acc0[r] += m2[r]; acc1[r] += m2[4 + r]; }
      l += m2[8];
    }
    float inv = 1.f / l;
    __bf16* crow = ctx + (size_t)(b * T_ + qt * 16 + lr) * D_ + h * 32 + kg * 4;
    #pragma unroll
    for (int r = 0; r < 4; r++) {
      crow[r]      = (__bf16)(acc0[r] * inv);
      crow[16 + r] = (__bf16)(acc1[r] * inv);
    }
  }
}

// ---------------------------------------------------------------------------
// Fused Wo + LN + FFN (+ final LN), N-split: 4 waves/block, wave w owns cols
// [w*32, w*32+32) through all three GEMMs (so the residual stays in-register).
// Cross-wave LN stats via statb; full-row t1/hres via block LDS transposes.
// ---------------------------------------------------------------------------
template <int LAST>
__global__ __launch_bounds__(256) void wo_ffn(
    const __bf16* __restrict__ ctxb, const __bf16* __restrict__ wto,
    const float* __restrict__ bo, const float* __restrict__ g1,
    const float* __restrict__ bt1, const __bf16* __restrict__ wt1,
    const float* __restrict__ b1, const __bf16* __restrict__ wt2,
    const float* __restrict__ b2, const float* __restrict__ g2,
    const float* __restrict__ bt2, __bf16* __restrict__ outb,
    float* __restrict__ outf)
{
  __shared__ __attribute__((aligned(16))) __bf16 tb0[16][128];
  __shared__ __attribute__((aligned(16))) __bf16 tb1[16][128];
  __shared__ float2 statb[16][4];

  int w = threadIdx.x >> 6, lane = threadIdx.x & 63;
  int m0 = blockIdx.x * 16;
  int lr = lane & 15, kg = lane >> 4;
  int swz = (lr & 7) << 3;

  const __bf16* arow = ctxb + (size_t)(m0 + lr) * D_ + kg * 8;
  bf16x8 af[4];
  #pragma unroll
  for (int ks = 0; ks < 4; ks++) af[ks] = *(const bf16x8*)(arow + ks * 32);

  // ---- Wo GEMM (2 nt tiles) ----
  f32x4 acc[2] = {{0, 0, 0, 0}, {0, 0, 0, 0}};
  #pragma unroll
  for (int i = 0; i < 2; i++) {
    const __bf16* wrow = wto + (size_t)((w * 2 + i) * 16 + lr) * D_ + kg * 8;
    #pragma unroll
    for (int ks = 0; ks < 4; ks++)
      acc[i] = __builtin_amdgcn_mfma_f32_16x16x32_bf16(af[ks], *(const bf16x8*)(wrow + ks * 32), acc[i], 0, 0, 0);
  }

  // ---- +bo, cross-wave LN stats ----
  float xv[2][4];
  float s[4] = {0, 0, 0, 0}, s2[4] = {0, 0, 0, 0};
  #pragma unroll
  for (int i = 0; i < 2; i++) {
    float bcol = bo[(w * 2 + i) * 16 + lr];
    #pragma unroll
    for (int r = 0; r < 4; r++) {
      float y = acc[i][r] + bcol;
      xv[i][r] = y; s[r] += y; s2[r] += y * y;
    }
  }
  #pragma unroll
  for (int r = 0; r < 4; r++)
    for (int mk = 1; mk < 16; mk <<= 1) {
      s[r] += __shfl_xor(s[r], mk, 64);
      s2[r] += __shfl_xor(s2[r], mk, 64);
    }
  if (lr == 0) {
    #pragma unroll
    for (int r = 0; r < 4; r++) statb[kg * 4 + r][w] = make_float2(s[r], s2[r]);
  }
  __syncthreads();
  float mu_[4], rstd_[4];
  #pragma unroll
  for (int r = 0; r < 4; r++) {
    int row = kg * 4 + r;
    float ss = 0.f, ss2 = 0.f;
    #pragma unroll
    for (int w2 = 0; w2 < 4; w2++) {
      float2 t = statb[row][w2];
      ss += t.x; ss2 += t.y;
    }
    mu_[r] = ss * (1.f / D_);
    float var = ss2 * (1.f / D_) - mu_[r] * mu_[r];
    rstd_[r] = rsqrtf(var + 1e-3f);
  }
  // hres = LN1 result (kept in regs for residual); transpose to tb0
  float hres[2][4];
  #pragma unroll
  for (int i = 0; i < 2; i++) {
    int col = (w * 2 + i) * 16 + lr;
    float gc = g1[col], bc = bt1[col];
    #pragma unroll
    for (int r = 0; r < 4; r++) {
      float y = (xv[i][r] - mu_[r]) * rstd_[r] * gc + bc;
      hres[i][r] = y;
      int row = kg * 4 + r;
      tb0[row][col ^ ((row & 7) << 3)] = (__bf16)y;
    }
  }
  __syncthreads();

  // ---- W1 + ReLU ----
  bf16x8 a2[4];
  #pragma unroll
  for (int ks = 0; ks < 4; ks++)
    a2[ks] = *(const bf16x8*)(&tb0[lr][(ks * 32 + kg * 8) ^ swz]);
  f32x4 acc2[2] = {{0, 0, 0, 0}, {0, 0, 0, 0}};
  #pragma unroll
  for (int i = 0; i < 2; i++) {
    const __bf16* wrow = wt1 + (size_t)((w * 2 + i) * 16 + lr) * D_ + kg * 8;
    #pragma unroll
    for (int ks = 0; ks < 4; ks++)
      acc2[i] = __builtin_amdgcn_mfma_f32_16x16x32_bf16(a2[ks], *(const bf16x8*)(wrow + ks * 32), acc2[i], 0, 0, 0);
  }
  #pragma unroll
  for (int i = 0; i < 2; i++) {
    float bcol = b1[(w * 2 + i) * 16 + lr];
    int col = (w * 2 + i) * 16 + lr;
    #pragma unroll
    for (int r = 0; r < 4; r++) {
      int row = kg * 4 + r;
      tb1[row][col ^ ((row & 7) << 3)] = (__bf16)fmaxf(acc2[i][r] + bcol, 0.f);
    }
  }
  __syncthreads();

  // ---- W2 + residual ----
  bf16x8 a3[4];
  #pragma unroll
  for (int ks = 0; ks < 4; ks++)
    a3[ks] = *(const bf16x8*)(&tb1[lr][(ks * 32 + kg * 8) ^ swz]);
  f32x4 acc3[2] = {{0, 0, 0, 0}, {0, 0, 0, 0}};
  #pragma unroll
  for (int i = 0; i < 2; i++) {
    const __bf16* wrow = wt2 + (size_t)((w * 2 + i) * 16 + lr) * D_ + kg * 8;
    #pragma unroll
    for (int ks = 0; ks < 4; ks++)
      acc3[i] = __builtin_amdgcn_mfma_f32_16x16x32_bf16(a3[ks], *(const bf16x8*)(wrow + ks * 32), acc3[i], 0, 0, 0);
  }

  if constexpr (LAST) {
    float yv[2][4];
    float t[4] = {0, 0, 0, 0}, t2[4] = {0, 0, 0, 0};
    #pragma unroll
    for (int i = 0; i < 2; i++) {
      float bcol = b2[(w * 2 + i) * 16 + lr];
      #pragma unroll
      for (int r = 0; r < 4; r++) {
        float y = acc3[i][r] + bcol + hres[i][r];
        yv[i][r] = y; t[r] += y; t2[r] += y * y;
      }
    }
    #pragma unroll
    for (int r = 0; r < 4; r++)
      for (int mk = 1; mk < 16; mk <<= 1) {
        t[r] += __shfl_xor(t[r], mk, 64);
        t2[r] += __shfl_xor(t2[r], mk, 64);
      }
    __syncthreads();   // ensure prior statb reads done before overwrite
    if (lr == 0) {
      #pragma unroll
      for (int r = 0; r < 4; r++) statb[kg * 4 + r][w] = make_float2(t[r], t2[r]);
    }
    __syncthreads();
    #pragma unroll
    for (int r = 0; r < 4; r++) {
      int row = kg * 4 + r;
      float ss = 0.f, ss2 = 0.f;
      #pragma unroll
      for (int w2 = 0; w2 < 4; w2++) {
        float2 tt = statb[row][w2];
        ss += tt.x; ss2 += tt.y;
      }
      float mu = ss * (1.f / D_);
      float var = ss2 * (1.f / D_) - mu * mu;
      float rstd = rsqrtf(var + 1e-3f);
      #pragma unroll
      for (int i = 0; i < 2; i++) {
        int col = (w * 2 + i) * 16 + lr;
        outf[(size_t)(m0 + row) * D_ + col] =
            (yv[i][r] - mu) * rstd * g2[col] + bt2[col];
      }
    }
  } else {
    #pragma unroll
    for (int i = 0; i < 2; i++) {
      int col = (w * 2 + i) * 16 + lr;
      float bcol = b2[col];
      #pragma unroll
      for (int r = 0; r < 4; r++)
        outb[(size_t)(m0 + kg * 4 + r) * D_ + col] =
            (__bf16)(acc3[i][r] + bcol + hres[i][r]);
    }
  }
}

// ---------------------------------------------------------------------------
extern "C" void kernel_launch(void* const* d_in, const int* in_sizes, int n_in,
                              void* d_out, int out_size, void* d_ws, size_t ws_size,
                              hipStream_t stream)
{
  const float* inputs = (const float*)d_in[0];
  const float* Wq = (const float*)d_in[1];
  const float* bq = (const float*)d_in[2];
  const float* Wk = (const float*)d_in[3];
  const float* bk = (const float*)d_in[4];
  const float* Wv = (const float*)d_in[5];
  const float* bv = (const float*)d_in[6];
  const float* Wo = (const float*)d_in[7];
  const float* bo = (const float*)d_in[8];
  const float* W1 = (const float*)d_in[9];
  const float* b1 = (const float*)d_in[10];
  const float* W2 = (const float*)d_in[11];
  const float* b2 = (const float*)d_in[12];
  const float* ln_g = (const float*)d_in[13];
  const float* ln_b = (const float*)d_in[14];
  float* out = (float*)d_out;

  char* ws = (char*)d_ws;
  size_t off = 0;
  auto alloc = [&](size_t bytes) {
    void* p = ws + off;
    off = (off + bytes + 255) & ~(size_t)255;
    return p;
  };
  const size_t ACT = (size_t)8192 * 128 * sizeof(__bf16);  // 2 MB
  __bf16* wt   = (__bf16*)alloc((size_t)6 * NB_ * 128 * 128 * sizeof(__bf16));
  __bf16* hbuf = (__bf16*)alloc(ACT);
  __bf16* qb   = (__bf16*)alloc(ACT);
  __bf16* kb   = (__bf16*)alloc(ACT);
  __bf16* vb   = (__bf16*)alloc(ACT);
  __bf16* ctxb = (__bf16*)alloc(ACT);

  prep_weights<<<768, 256, 0, stream>>>(Wq, Wk, Wv, Wo, W1, W2, wt);
  posadd<<<2048, 256, 0, stream>>>(inputs, hbuf);

  for (int i = 0; i < NB_; i++) {
    const __bf16* wtq = wt + (size_t)(0 * NB_ + i) * 16384;
    const __bf16* wtk = wt + (size_t)(1 * NB_ + i) * 16384;
    const __bf16* wtv = wt + (size_t)(2 * NB_ + i) * 16384;
    const __bf16* wto = wt + (size_t)(3 * NB_ + i) * 16384;
    const __bf16* wt1 = wt + (size_t)(4 * NB_ + i) * 16384;
    const __bf16* wt2 = wt + (size_t)(5 * NB_ + i) * 16384;

    lnqkv<<<512, 256, 0, stream>>>(hbuf, wtq, wtk, wtv,
                                   bq + i * 128, bk + i * 128, bv + i * 128,
                                   ln_g + (size_t)(2 * i) * 128, ln_b + (size_t)(2 * i) * 128,
                                   qb, kb, vb);
    attn4<<<2048, 256, 0, stream>>>(qb, kb, vb, ctxb);
    if (i == 0) {
      wo_ffn<0><<<512, 256, 0, stream>>>(ctxb, wto, bo + i * 128,
                                         ln_g + 1 * 128, ln_b + 1 * 128,
                                         wt1, b1 + i * 128, wt2, b2 + i * 128,
                                         nullptr, nullptr, hbuf, nullptr);
    } else {
      wo_ffn<1><<<512, 256, 0, stream>>>(ctxb, wto, bo + i * 128,
                                         ln_g + 3 * 128, ln_b + 3 * 128,
                                         wt1, b1 + i * 128, wt2, b2 + i * 128,
                                         ln_g + 3 * 128, ln_b + 3 * 128,
                                         nullptr, out);
    }
  }
}

// Round 8
// 207.116 us; speedup vs baseline: 1.3391x; 1.2334x over previous
//
#include <hip/hip_runtime.h>
#include <hip/hip_bf16.h>

typedef __bf16 bf16x8 __attribute__((ext_vector_type(8)));
typedef __bf16 bf16x4 __attribute__((ext_vector_type(4)));
typedef float f32x4 __attribute__((ext_vector_type(4)));
typedef float f32x16 __attribute__((ext_vector_type(16)));
typedef unsigned int u32x4v __attribute__((ext_vector_type(4)));

#define D_ 128
#define T_ 2048
#define B_ 4
#define H_ 4
#define NB_ 2

// ---------------------------------------------------------------------------
// Weight prep: fp32 [NB][128][128] (k-major) -> bf16 transposed Wt[j][i][n][k]
// ---------------------------------------------------------------------------
__global__ __launch_bounds__(256) void prep_weights(
    const float* __restrict__ Wq, const float* __restrict__ Wk,
    const float* __restrict__ Wv, const float* __restrict__ Wo,
    const float* __restrict__ W1, const float* __restrict__ W2,
    __bf16* __restrict__ wt)
{
  int tid = blockIdx.x * 256 + threadIdx.x;   // < 6*NB*128*128
  int j   = tid >> 15;
  int rem = tid & 32767;
  int i   = rem >> 14;
  int n   = (rem >> 7) & 127;
  int kk  = rem & 127;
  const float* srcs[6] = {Wq, Wk, Wv, Wo, W1, W2};
  wt[tid] = (__bf16)srcs[j][i * 16384 + kk * 128 + n];
}

// ---------------------------------------------------------------------------
// h0 = bf16(inputs + pos_encoding). One wave per row (2 cols/lane).
// ---------------------------------------------------------------------------
__global__ __launch_bounds__(256) void posadd(
    const float* __restrict__ x, __bf16* __restrict__ out)
{
  int w = threadIdx.x >> 6, lane = threadIdx.x & 63;
  int row = blockIdx.x * 4 + w;
  int t = row & (T_ - 1);
  #pragma unroll
  for (int e = 0; e < 2; e++) {
    int c = lane * 2 + e;
    float arg = (float)t * exp2f(-0.20762050593045952f * (float)c);
    float pe = (c & 1) ? cosf(arg) : sinf(arg);
    out[row * D_ + c] = (__bf16)(x[row * D_ + c] + pe);
  }
}

// ---------------------------------------------------------------------------
// Fused LN + QKV, N-split: 4 waves/block, wave w computes cols [w*32, w*32+32)
// of Q, K, V for the block's 16 rows. LN in-register from A-frags.
// mfma_f32_16x16x32_bf16 layouts:
//   A: lane holds A[lane%16][8*(lane/16)+e]   (+32 per k-step)
//   B: lane holds B[8*(lane/16)+e][lane%16]
//   C/D: lane holds D[(lane/16)*4+r][lane%16]
// ---------------------------------------------------------------------------
__global__ __launch_bounds__(256) void lnqkv(
    const __bf16* __restrict__ hsrc, const __bf16* __restrict__ wtq,
    const __bf16* __restrict__ wtk, const __bf16* __restrict__ wtv,
    const float* __restrict__ bq, const float* __restrict__ bk,
    const float* __restrict__ bv, const float* __restrict__ g,
    const float* __restrict__ beta,
    __bf16* __restrict__ qo, __bf16* __restrict__ ko, __bf16* __restrict__ vo)
{
  int w = threadIdx.x >> 6, lane = threadIdx.x & 63;
  int m0 = blockIdx.x * 16;
  int lr = lane & 15, kg = lane >> 4;

  const __bf16* arow = hsrc + (size_t)(m0 + lr) * D_ + kg * 8;
  bf16x8 araw[4];
  #pragma unroll
  for (int ks = 0; ks < 4; ks++) araw[ks] = *(const bf16x8*)(arow + ks * 32);

  float s = 0.f, s2 = 0.f;
  #pragma unroll
  for (int ks = 0; ks < 4; ks++)
    #pragma unroll
    for (int e = 0; e < 8; e++) {
      float x = (float)araw[ks][e];
      s += x; s2 += x * x;
    }
  s += __shfl_xor(s, 16, 64);  s2 += __shfl_xor(s2, 16, 64);
  s += __shfl_xor(s, 32, 64);  s2 += __shfl_xor(s2, 32, 64);
  float mu = s * (1.f / D_);
  float var = s2 * (1.f / D_) - mu * mu;
  float rstd = rsqrtf(var + 1e-3f);

  bf16x8 af[4];
  #pragma unroll
  for (int ks = 0; ks < 4; ks++) {
    int c0 = ks * 32 + kg * 8;
    float4 g0 = *(const float4*)(g + c0), g1 = *(const float4*)(g + c0 + 4);
    float4 q0 = *(const float4*)(beta + c0), q1 = *(const float4*)(beta + c0 + 4);
    const float* gp[2] = {&g0.x, &g1.x};
    const float* bp[2] = {&q0.x, &q1.x};
    #pragma unroll
    for (int e = 0; e < 8; e++)
      af[ks][e] = (__bf16)(((float)araw[ks][e] - mu) * rstd * gp[e >> 2][e & 3] + bp[e >> 2][e & 3]);
  }

  #pragma unroll
  for (int i = 0; i < 2; i++) {
    int nt = w * 2 + i;
    const __bf16* wq = wtq + (size_t)(nt * 16 + lr) * D_ + kg * 8;
    const __bf16* wk = wtk + (size_t)(nt * 16 + lr) * D_ + kg * 8;
    const __bf16* wv = wtv + (size_t)(nt * 16 + lr) * D_ + kg * 8;
    f32x4 aq = {0, 0, 0, 0}, ak = {0, 0, 0, 0}, av = {0, 0, 0, 0};
    #pragma unroll
    for (int ks = 0; ks < 4; ks++) {
      aq = __builtin_amdgcn_mfma_f32_16x16x32_bf16(af[ks], *(const bf16x8*)(wq + ks * 32), aq, 0, 0, 0);
      ak = __builtin_amdgcn_mfma_f32_16x16x32_bf16(af[ks], *(const bf16x8*)(wk + ks * 32), ak, 0, 0, 0);
      av = __builtin_amdgcn_mfma_f32_16x16x32_bf16(af[ks], *(const bf16x8*)(wv + ks * 32), av, 0, 0, 0);
    }
    int col = nt * 16 + lr;
    float bqc = bq[col], bkc = bk[col], bvc = bv[col];
    int hh = col >> 5, dk = col & 31;
    #pragma unroll
    for (int r = 0; r < 4; r++) {
      int row = m0 + kg * 4 + r;
      qo[(size_t)row * D_ + col] = (__bf16)(aq[r] + bqc);
      ko[(size_t)row * D_ + col] = (__bf16)(ak[r] + bkc);
      int bb = row >> 11, t = row & (T_ - 1);
      vo[((size_t)(bb * H_ + hh) * 32 + dk) * T_ + t] = (__bf16)(av[r] + bvc);
    }
  }
}

// ---------------------------------------------------------------------------
// Flash attention v5: 32x32 swapped structure, fully in-register softmax.
//   S^T[32k,32q] = mfma_32x32x16(K,Q) x2 (DK=32 split into two K=16 steps).
//   32x32 layouts: A: lane holds A[lane%32][8*(lane/32)+e]
//                  B: lane holds B[8*(lane/32)+e][lane%32]
//                  C/D: col=lane%32, row=(r&3)+8*(r>>2)+4*(lane/32), r=0..15
//   -> lane owns q-col lq=lane&31 with 16 key-rows in regs. Fixed-max softmax
//   p=exp2(s-24) (validated attn4; scores O(1) post-LN, acc/l cancels scale).
//   P^T B-frags built in-register: cvt_pk_bf16_f32 pairs + shfl_xor(32) +
//   half-select redistribute key halves across lane<32/lane>=32. No LDS in
//   the loop. PV: O^T = mfma(V^T, P^T) x2. 4-way KV split, merged once.
//   XCD swizzle: bh = blk&15 keeps each (b,h)'s 256KB K/V on one XCD's L2.
// ---------------------------------------------------------------------------
__global__ __launch_bounds__(256) void attn5(
    const __bf16* __restrict__ q, const __bf16* __restrict__ k,
    const __bf16* __restrict__ vT, __bf16* __restrict__ ctx)
{
  __shared__ float mbuf[3][64][17];

  int w = threadIdx.x >> 6, lane = threadIdx.x & 63;
  int bh = blockIdx.x & 15, qt = blockIdx.x >> 4;   // qt 0..63
  int b = bh >> 2, h = bh & 3;
  int lq = lane & 31, hi = lane >> 5;

  const float qscale = 0.17677669529663687f * 1.4426950408889634f;  // 1/sqrt(32)*log2e
  const __bf16* qrow = q + (size_t)(b * T_ + qt * 32 + lq) * D_ + h * 32 + hi * 8;
  bf16x8 qraw0 = *(const bf16x8*)(qrow);
  bf16x8 qraw1 = *(const bf16x8*)(qrow + 16);
  bf16x8 qf0, qf1;
  #pragma unroll
  for (int e = 0; e < 8; e++) {
    qf0[e] = (__bf16)((float)qraw0[e] * qscale);
    qf1[e] = (__bf16)((float)qraw1[e] * qscale);
  }

  const __bf16* kbase = k + (size_t)(b * T_) * D_ + h * 32 + hi * 8;
  const __bf16* vbase = vT + ((size_t)(b * H_ + h) * 32 + lq) * T_ + hi * 8;

  f32x16 acc;
  #pragma unroll
  for (int r = 0; r < 16; r++) acc[r] = 0.f;
  float l = 0.f;

  int kk = w * 512;
  bf16x8 kf0 = *(const bf16x8*)(kbase + (size_t)(kk + lq) * D_);
  bf16x8 kf1 = *(const bf16x8*)(kbase + (size_t)(kk + lq) * D_ + 16);
  bf16x8 vf0 = *(const bf16x8*)(vbase + kk);
  bf16x8 vf1 = *(const bf16x8*)(vbase + kk + 16);

  for (int it = 0; it < 16; it++) {
    __builtin_amdgcn_s_setprio(1);
    f32x16 s;
    #pragma unroll
    for (int r = 0; r < 16; r++) s[r] = 0.f;
    s = __builtin_amdgcn_mfma_f32_32x32x16_bf16(kf0, qf0, s, 0, 0, 0);
    s = __builtin_amdgcn_mfma_f32_32x32x16_bf16(kf1, qf1, s, 0, 0, 0);
    __builtin_amdgcn_s_setprio(0);

    bf16x8 kn0, kn1, vn0, vn1;
    if (it < 15) {
      int k2 = kk + 32;
      kn0 = *(const bf16x8*)(kbase + (size_t)(k2 + lq) * D_);
      kn1 = *(const bf16x8*)(kbase + (size_t)(k2 + lq) * D_ + 16);
      vn0 = *(const bf16x8*)(vbase + k2);
      vn1 = *(const bf16x8*)(vbase + k2 + 16);
    }

    // fixed-max softmax + bf16 pack, all in-register.
    // reg r -> key row (r&3) + 8*(r>>2) + 4*hi of this 32-key tile.
    unsigned int aw[8];
    #pragma unroll
    for (int g = 0; g < 4; g++) {
      float p0 = exp2f(s[g * 4 + 0] - 24.f);
      float p1 = exp2f(s[g * 4 + 1] - 24.f);
      float p2 = exp2f(s[g * 4 + 2] - 24.f);
      float p3 = exp2f(s[g * 4 + 3] - 24.f);
      l += (p0 + p1) + (p2 + p3);
      unsigned int u01, u23;
      asm("v_cvt_pk_bf16_f32 %0, %1, %2" : "=v"(u01) : "v"(p0), "v"(p1));
      asm("v_cvt_pk_bf16_f32 %0, %1, %2" : "=v"(u23) : "v"(p2), "v"(p3));
      aw[g * 2] = u01; aw[g * 2 + 1] = u23;
    }
    // redistribute halves: B-frag dword e-pair {2j, 2j+1} of keys 8*hi+...
    // own aw[g] covers keys {..}+4*hi; partner (lane^32) holds the other half.
    unsigned int w0, w1, w2, w3;
    {
      unsigned int sa = __shfl_xor(aw[0], 32, 64), sb = __shfl_xor(aw[2], 32, 64);
      w0 = hi ? sb : aw[0];  w2 = hi ? aw[2] : sa;
      sa = __shfl_xor(aw[1], 32, 64); sb = __shfl_xor(aw[3], 32, 64);
      w1 = hi ? sb : aw[1];  w3 = hi ? aw[3] : sa;
    }
    bf16x8 pw0 = __builtin_bit_cast(bf16x8, (u32x4v){w0, w1, w2, w3});
    {
      unsigned int sa = __shfl_xor(aw[4], 32, 64), sb = __shfl_xor(aw[6], 32, 64);
      w0 = hi ? sb : aw[4];  w2 = hi ? aw[6] : sa;
      sa = __shfl_xor(aw[5], 32, 64); sb = __shfl_xor(aw[7], 32, 64);
      w1 = hi ? sb : aw[5];  w3 = hi ? aw[7] : sa;
    }
    bf16x8 pw1 = __builtin_bit_cast(bf16x8, (u32x4v){w0, w1, w2, w3});

    __builtin_amdgcn_s_setprio(1);
    acc = __builtin_amdgcn_mfma_f32_32x32x16_bf16(vf0, pw0, acc, 0, 0, 0);
    acc = __builtin_amdgcn_mfma_f32_32x32x16_bf16(vf1, pw1, acc, 0, 0, 0);
    __builtin_amdgcn_s_setprio(0);

    kf0 = kn0; kf1 = kn1; vf0 = vn0; vf1 = vn1;
    kk += 32;
  }

  // combine the two lane-halves' l per q-column
  l += __shfl_xor(l, 32, 64);

  if (w > 0) {
    float* mb = &mbuf[w - 1][lane][0];
    #pragma unroll
    for (int r = 0; r < 16; r++) mb[r] = acc[r];
    mb[16] = l;
  }
  __syncthreads();
  if (w == 0) {
    #pragma unroll
    for (int w2_ = 0; w2_ < 3; w2_++) {
      const float* mb = &mbuf[w2_][lane][0];
      #pragma unroll
      for (int r = 0; r < 16; r++) acc[r] += mb[r];
      l += mb[16];
    }
    float inv = 1.f / l;
    // lane holds O^T[dk][q=lq], dk = g*8 + 4*hi + j
    __bf16* crow = ctx + (size_t)(b * T_ + qt * 32 + lq) * D_ + h * 32 + hi * 4;
    #pragma unroll
    for (int g = 0; g < 4; g++) {
      bf16x4 o;
      #pragma unroll
      for (int j = 0; j < 4; j++) o[j] = (__bf16)(acc[g * 4 + j] * inv);
      *(bf16x4*)(crow + g * 8) = o;
    }
  }
}

// ---------------------------------------------------------------------------
// Fused Wo + LN + FFN (+ final LN), N-split: 4 waves/block, wave w owns cols
// [w*32, w*32+32) through all three GEMMs (residual stays in-register).
// ---------------------------------------------------------------------------
template <int LAST>
__global__ __launch_bounds__(256) void wo_ffn(
    const __bf16* __restrict__ ctxb, const __bf16* __restrict__ wto,
    const float* __restrict__ bo, const float* __restrict__ g1,
    const float* __restrict__ bt1, const __bf16* __restrict__ wt1,
    const float* __restrict__ b1, const __bf16* __restrict__ wt2,
    const float* __restrict__ b2, const float* __restrict__ g2,
    const float* __restrict__ bt2, __bf16* __restrict__ outb,
    float* __restrict__ outf)
{
  __shared__ __attribute__((aligned(16))) __bf16 tb0[16][128];
  __shared__ __attribute__((aligned(16))) __bf16 tb1[16][128];
  __shared__ float2 statb[16][4];

  int w = threadIdx.x >> 6, lane = threadIdx.x & 63;
  int m0 = blockIdx.x * 16;
  int lr = lane & 15, kg = lane >> 4;
  int swz = (lr & 7) << 3;

  const __bf16* arow = ctxb + (size_t)(m0 + lr) * D_ + kg * 8;
  bf16x8 af[4];
  #pragma unroll
  for (int ks = 0; ks < 4; ks++) af[ks] = *(const bf16x8*)(arow + ks * 32);

  f32x4 acc[2] = {{0, 0, 0, 0}, {0, 0, 0, 0}};
  #pragma unroll
  for (int i = 0; i < 2; i++) {
    const __bf16* wrow = wto + (size_t)((w * 2 + i) * 16 + lr) * D_ + kg * 8;
    #pragma unroll
    for (int ks = 0; ks < 4; ks++)
      acc[i] = __builtin_amdgcn_mfma_f32_16x16x32_bf16(af[ks], *(const bf16x8*)(wrow + ks * 32), acc[i], 0, 0, 0);
  }

  float xv[2][4];
  float s[4] = {0, 0, 0, 0}, s2[4] = {0, 0, 0, 0};
  #pragma unroll
  for (int i = 0; i < 2; i++) {
    float bcol = bo[(w * 2 + i) * 16 + lr];
    #pragma unroll
    for (int r = 0; r < 4; r++) {
      float y = acc[i][r] + bcol;
      xv[i][r] = y; s[r] += y; s2[r] += y * y;
    }
  }
  #pragma unroll
  for (int r = 0; r < 4; r++)
    for (int mk = 1; mk < 16; mk <<= 1) {
      s[r] += __shfl_xor(s[r], mk, 64);
      s2[r] += __shfl_xor(s2[r], mk, 64);
    }
  if (lr == 0) {
    #pragma unroll
    for (int r = 0; r < 4; r++) statb[kg * 4 + r][w] = make_float2(s[r], s2[r]);
  }
  __syncthreads();
  float mu_[4], rstd_[4];
  #pragma unroll
  for (int r = 0; r < 4; r++) {
    int row = kg * 4 + r;
    float ss = 0.f, ss2 = 0.f;
    #pragma unroll
    for (int w2 = 0; w2 < 4; w2++) {
      float2 t = statb[row][w2];
      ss += t.x; ss2 += t.y;
    }
    mu_[r] = ss * (1.f / D_);
    float var = ss2 * (1.f / D_) - mu_[r] * mu_[r];
    rstd_[r] = rsqrtf(var + 1e-3f);
  }
  float hres[2][4];
  #pragma unroll
  for (int i = 0; i < 2; i++) {
    int col = (w * 2 + i) * 16 + lr;
    float gc = g1[col], bc = bt1[col];
    #pragma unroll
    for (int r = 0; r < 4; r++) {
      float y = (xv[i][r] - mu_[r]) * rstd_[r] * gc + bc;
      hres[i][r] = y;
      int row = kg * 4 + r;
      tb0[row][col ^ ((row & 7) << 3)] = (__bf16)y;
    }
  }
  __syncthreads();

  bf16x8 a2[4];
  #pragma unroll
  for (int ks = 0; ks < 4; ks++)
    a2[ks] = *(const bf16x8*)(&tb0[lr][(ks * 32 + kg * 8) ^ swz]);
  f32x4 acc2[2] = {{0, 0, 0, 0}, {0, 0, 0, 0}};
  #pragma unroll
  for (int i = 0; i < 2; i++) {
    const __bf16* wrow = wt1 + (size_t)((w * 2 + i) * 16 + lr) * D_ + kg * 8;
    #pragma unroll
    for (int ks = 0; ks < 4; ks++)
      acc2[i] = __builtin_amdgcn_mfma_f32_16x16x32_bf16(a2[ks], *(const bf16x8*)(wrow + ks * 32), acc2[i], 0, 0, 0);
  }
  #pragma unroll
  for (int i = 0; i < 2; i++) {
    float bcol = b1[(w * 2 + i) * 16 + lr];
    int col = (w * 2 + i) * 16 + lr;
    #pragma unroll
    for (int r = 0; r < 4; r++) {
      int row = kg * 4 + r;
      tb1[row][col ^ ((row & 7) << 3)] = (__bf16)fmaxf(acc2[i][r] + bcol, 0.f);
    }
  }
  __syncthreads();

  bf16x8 a3[4];
  #pragma unroll
  for (int ks = 0; ks < 4; ks++)
    a3[ks] = *(const bf16x8*)(&tb1[lr][(ks * 32 + kg * 8) ^ swz]);
  f32x4 acc3[2] = {{0, 0, 0, 0}, {0, 0, 0, 0}};
  #pragma unroll
  for (int i = 0; i < 2; i++) {
    const __bf16* wrow = wt2 + (size_t)((w * 2 + i) * 16 + lr) * D_ + kg * 8;
    #pragma unroll
    for (int ks = 0; ks < 4; ks++)
      acc3[i] = __builtin_amdgcn_mfma_f32_16x16x32_bf16(a3[ks], *(const bf16x8*)(wrow + ks * 32), acc3[i], 0, 0, 0);
  }

  if constexpr (LAST) {
    float yv[2][4];
    float t[4] = {0, 0, 0, 0}, t2[4] = {0, 0, 0, 0};
    #pragma unroll
    for (int i = 0; i < 2; i++) {
      float bcol = b2[(w * 2 + i) * 16 + lr];
      #pragma unroll
      for (int r = 0; r < 4; r++) {
        float y = acc3[i][r] + bcol + hres[i][r];
        yv[i][r] = y; t[r] += y; t2[r] += y * y;
      }
    }
    #pragma unroll
    for (int r = 0; r < 4; r++)
      for (int mk = 1; mk < 16; mk <<= 1) {
        t[r] += __shfl_xor(t[r], mk, 64);
        t2[r] += __shfl_xor(t2[r], mk, 64);
      }
    __syncthreads();
    if (lr == 0) {
      #pragma unroll
      for (int r = 0; r < 4; r++) statb[kg * 4 + r][w] = make_float2(t[r], t2[r]);
    }
    __syncthreads();
    #pragma unroll
    for (int r = 0; r < 4; r++) {
      int row = kg * 4 + r;
      float ss = 0.f, ss2 = 0.f;
      #pragma unroll
      for (int w2 = 0; w2 < 4; w2++) {
        float2 tt = statb[row][w2];
        ss += tt.x; ss2 += tt.y;
      }
      float mu = ss * (1.f / D_);
      float var = ss2 * (1.f / D_) - mu * mu;
      float rstd = rsqrtf(var + 1e-3f);
      #pragma unroll
      for (int i = 0; i < 2; i++) {
        int col = (w * 2 + i) * 16 + lr;
        outf[(size_t)(m0 + row) * D_ + col] =
            (yv[i][r] - mu) * rstd * g2[col] + bt2[col];
      }
    }
  } else {
    #pragma unroll
    for (int i = 0; i < 2; i++) {
      int col = (w * 2 + i) * 16 + lr;
      float bcol = b2[col];
      #pragma unroll
      for (int r = 0; r < 4; r++)
        outb[(size_t)(m0 + kg * 4 + r) * D_ + col] =
            (__bf16)(acc3[i][r] + bcol + hres[i][r]);
    }
  }
}

// ---------------------------------------------------------------------------
extern "C" void kernel_launch(void* const* d_in, const int* in_sizes, int n_in,
                              void* d_out, int out_size, void* d_ws, size_t ws_size,
                              hipStream_t stream)
{
  const float* inputs = (const float*)d_in[0];
  const float* Wq = (const float*)d_in[1];
  const float* bq = (const float*)d_in[2];
  const float* Wk = (const float*)d_in[3];
  const float* bk = (const float*)d_in[4];
  const float* Wv = (const float*)d_in[5];
  const float* bv = (const float*)d_in[6];
  const float* Wo = (const float*)d_in[7];
  const float* bo = (const float*)d_in[8];
  const float* W1 = (const float*)d_in[9];
  const float* b1 = (const float*)d_in[10];
  const float* W2 = (const float*)d_in[11];
  const float* b2 = (const float*)d_in[12];
  const float* ln_g = (const float*)d_in[13];
  const float* ln_b = (const float*)d_in[14];
  float* out = (float*)d_out;

  char* ws = (char*)d_ws;
  size_t off = 0;
  auto alloc = [&](size_t bytes) {
    void* p = ws + off;
    off = (off + bytes + 255) & ~(size_t)255;
    return p;
  };
  const size_t ACT = (size_t)8192 * 128 * sizeof(__bf16);  // 2 MB
  __bf16* wt   = (__bf16*)alloc((size_t)6 * NB_ * 128 * 128 * sizeof(__bf16));
  __bf16* hbuf = (__bf16*)alloc(ACT);
  __bf16* qb   = (__bf16*)alloc(ACT);
  __bf16* kb   = (__bf16*)alloc(ACT);
  __bf16* vb   = (__bf16*)alloc(ACT);
  __bf16* ctxb = (__bf16*)alloc(ACT);

  prep_weights<<<768, 256, 0, stream>>>(Wq, Wk, Wv, Wo, W1, W2, wt);
  posadd<<<2048, 256, 0, stream>>>(inputs, hbuf);

  for (int i = 0; i < NB_; i++) {
    const __bf16* wtq = wt + (size_t)(0 * NB_ + i) * 16384;
    const __bf16* wtk = wt + (size_t)(1 * NB_ + i) * 16384;
    const __bf16* wtv = wt + (size_t)(2 * NB_ + i) * 16384;
    const __bf16* wto = wt + (size_t)(3 * NB_ + i) * 16384;
    const __bf16* wt1 = wt + (size_t)(4 * NB_ + i) * 16384;
    const __bf16* wt2 = wt + (size_t)(5 * NB_ + i) * 16384;

    lnqkv<<<512, 256, 0, stream>>>(hbuf, wtq, wtk, wtv,
                                   bq + i * 128, bk + i * 128, bv + i * 128,
                                   ln_g + (size_t)(2 * i) * 128, ln_b + (size_t)(2 * i) * 128,
                                   qb, kb, vb);
    attn5<<<1024, 256, 0, stream>>>(qb, kb, vb, ctxb);
    if (i == 0) {
      wo_ffn<0><<<512, 256, 0, stream>>>(ctxb, wto, bo + i * 128,
                                         ln_g + 1 * 128, ln_b + 1 * 128,
                                         wt1, b1 + i * 128, wt2, b2 + i * 128,
                                         nullptr, nullptr, hbuf, nullptr);
    } else {
      wo_ffn<1><<<512, 256, 0, stream>>>(ctxb, wto, bo + i * 128,
                                         ln_g + 3 * 128, ln_b + 3 * 128,
                                         wt1, b1 + i * 128, wt2, b2 + i * 128,
                                         ln_g + 3 * 128, ln_b + 3 * 128,
                                         nullptr, out);
    }
  }
}

// Round 9
// 198.682 us; speedup vs baseline: 1.3959x; 1.0424x over previous
//
#include <hip/hip_runtime.h>
#include <hip/hip_bf16.h>

typedef __bf16 bf16x8 __attribute__((ext_vector_type(8)));
typedef __bf16 bf16x4 __attribute__((ext_vector_type(4)));
typedef float f32x4 __attribute__((ext_vector_type(4)));
typedef float f32x16 __attribute__((ext_vector_type(16)));
typedef unsigned int u32x4v __attribute__((ext_vector_type(4)));

#define D_ 128
#define T_ 2048
#define B_ 4
#define H_ 4
#define NB_ 2

// ---------------------------------------------------------------------------
// Weight prep: fp32 [NB][128][128] (k-major) -> bf16 transposed Wt[j][i][n][k]
// Thread mapping: fast dim = source column n -> coalesced READS; the
// scattered writes (stride 256B) don't stall the pipeline.
// ---------------------------------------------------------------------------
__global__ __launch_bounds__(256) void prep_weights(
    const float* __restrict__ Wq, const float* __restrict__ Wk,
    const float* __restrict__ Wv, const float* __restrict__ Wo,
    const float* __restrict__ W1, const float* __restrict__ W2,
    __bf16* __restrict__ wt)
{
  int tid = blockIdx.x * 256 + threadIdx.x;   // < 6*NB*128*128
  int j   = tid >> 15;
  int rem = tid & 32767;
  int i   = rem >> 14;
  int kk  = (rem >> 7) & 127;   // source row (slow)
  int n   = rem & 127;          // source col (fast) -> coalesced read
  const float* srcs[6] = {Wq, Wk, Wv, Wo, W1, W2};
  wt[(size_t)(j * NB_ + i) * 16384 + n * 128 + kk] =
      (__bf16)srcs[j][i * 16384 + kk * 128 + n];
}

// ---------------------------------------------------------------------------
// h0 = bf16(inputs + pos_encoding). One wave per row (2 cols/lane).
// ---------------------------------------------------------------------------
__global__ __launch_bounds__(256) void posadd(
    const float* __restrict__ x, __bf16* __restrict__ out)
{
  int w = threadIdx.x >> 6, lane = threadIdx.x & 63;
  int row = blockIdx.x * 4 + w;
  int t = row & (T_ - 1);
  #pragma unroll
  for (int e = 0; e < 2; e++) {
    int c = lane * 2 + e;
    float arg = (float)t * exp2f(-0.20762050593045952f * (float)c);
    float pe = (c & 1) ? cosf(arg) : sinf(arg);
    out[row * D_ + c] = (__bf16)(x[row * D_ + c] + pe);
  }
}

// ---------------------------------------------------------------------------
// Fused LN + QKV, N-split: 4 waves/block, wave w computes cols [w*32, w*32+32)
// of Q, K, V for the block's 16 rows. LN in-register from A-frags.
// mfma_f32_16x16x32_bf16 layouts:
//   A: lane holds A[lane%16][8*(lane/16)+e]   (+32 per k-step)
//   B: lane holds B[8*(lane/16)+e][lane%16]
//   C/D: lane holds D[(lane/16)*4+r][lane%16]
// ---------------------------------------------------------------------------
__global__ __launch_bounds__(256) void lnqkv(
    const __bf16* __restrict__ hsrc, const __bf16* __restrict__ wtq,
    const __bf16* __restrict__ wtk, const __bf16* __restrict__ wtv,
    const float* __restrict__ bq, const float* __restrict__ bk,
    const float* __restrict__ bv, const float* __restrict__ g,
    const float* __restrict__ beta,
    __bf16* __restrict__ qo, __bf16* __restrict__ ko, __bf16* __restrict__ vo)
{
  int w = threadIdx.x >> 6, lane = threadIdx.x & 63;
  int m0 = blockIdx.x * 16;
  int lr = lane & 15, kg = lane >> 4;

  const __bf16* arow = hsrc + (size_t)(m0 + lr) * D_ + kg * 8;
  bf16x8 araw[4];
  #pragma unroll
  for (int ks = 0; ks < 4; ks++) araw[ks] = *(const bf16x8*)(arow + ks * 32);

  float s = 0.f, s2 = 0.f;
  #pragma unroll
  for (int ks = 0; ks < 4; ks++)
    #pragma unroll
    for (int e = 0; e < 8; e++) {
      float x = (float)araw[ks][e];
      s += x; s2 += x * x;
    }
  s += __shfl_xor(s, 16, 64);  s2 += __shfl_xor(s2, 16, 64);
  s += __shfl_xor(s, 32, 64);  s2 += __shfl_xor(s2, 32, 64);
  float mu = s * (1.f / D_);
  float var = s2 * (1.f / D_) - mu * mu;
  float rstd = rsqrtf(var + 1e-3f);

  bf16x8 af[4];
  #pragma unroll
  for (int ks = 0; ks < 4; ks++) {
    int c0 = ks * 32 + kg * 8;
    float4 g0 = *(const float4*)(g + c0), g1 = *(const float4*)(g + c0 + 4);
    float4 q0 = *(const float4*)(beta + c0), q1 = *(const float4*)(beta + c0 + 4);
    const float* gp[2] = {&g0.x, &g1.x};
    const float* bp[2] = {&q0.x, &q1.x};
    #pragma unroll
    for (int e = 0; e < 8; e++)
      af[ks][e] = (__bf16)(((float)araw[ks][e] - mu) * rstd * gp[e >> 2][e & 3] + bp[e >> 2][e & 3]);
  }

  #pragma unroll
  for (int i = 0; i < 2; i++) {
    int nt = w * 2 + i;
    const __bf16* wq = wtq + (size_t)(nt * 16 + lr) * D_ + kg * 8;
    const __bf16* wk = wtk + (size_t)(nt * 16 + lr) * D_ + kg * 8;
    const __bf16* wv = wtv + (size_t)(nt * 16 + lr) * D_ + kg * 8;
    f32x4 aq = {0, 0, 0, 0}, ak = {0, 0, 0, 0}, av = {0, 0, 0, 0};
    #pragma unroll
    for (int ks = 0; ks < 4; ks++) {
      aq = __builtin_amdgcn_mfma_f32_16x16x32_bf16(af[ks], *(const bf16x8*)(wq + ks * 32), aq, 0, 0, 0);
      ak = __builtin_amdgcn_mfma_f32_16x16x32_bf16(af[ks], *(const bf16x8*)(wk + ks * 32), ak, 0, 0, 0);
      av = __builtin_amdgcn_mfma_f32_16x16x32_bf16(af[ks], *(const bf16x8*)(wv + ks * 32), av, 0, 0, 0);
    }
    int col = nt * 16 + lr;
    float bqc = bq[col], bkc = bk[col], bvc = bv[col];
    int hh = col >> 5, dk = col & 31;
    #pragma unroll
    for (int r = 0; r < 4; r++) {
      int row = m0 + kg * 4 + r;
      qo[(size_t)row * D_ + col] = (__bf16)(aq[r] + bqc);
      ko[(size_t)row * D_ + col] = (__bf16)(ak[r] + bkc);
      int bb = row >> 11, t = row & (T_ - 1);
      vo[((size_t)(bb * H_ + hh) * 32 + dk) * T_ + t] = (__bf16)(av[r] + bvc);
    }
  }
}

// ---------------------------------------------------------------------------
// Flash attention v6: 32x32 swapped structure, in-register fixed-max softmax.
//   S^T[32k,32q] = mfma_32x32x16(K,Q) x2, C initialized to -24 (folds the
//   fixed-max bias into the MFMA for free). p = v_exp_f32(s) directly
//   (raw builtin, args in [-50,0] — no range handling needed).
//   P^T B-frag redistribution: v_permlane32_swap_b32 (1 full-rate VALU op)
//   replaces shfl_xor(32)+select pairs:
//     swap(A,B): A' = {A.lo, B.lo} = w_lo-frag, B' = {A.hi, B.hi} = w_hi-frag.
//   No LDS in the loop. PV: O^T = mfma(V^T, P^T) x2. 4-way KV split/block,
//   merged once. XCD swizzle: bh = blk&15 keeps each (b,h)'s K/V on one XCD.
// ---------------------------------------------------------------------------
__global__ __launch_bounds__(256) void attn6(
    const __bf16* __restrict__ q, const __bf16* __restrict__ k,
    const __bf16* __restrict__ vT, __bf16* __restrict__ ctx)
{
  __shared__ float mbuf[3][64][17];

  int w = threadIdx.x >> 6, lane = threadIdx.x & 63;
  int bh = blockIdx.x & 15, qt = blockIdx.x >> 4;   // qt 0..63
  int b = bh >> 2, h = bh & 3;
  int lq = lane & 31, hi = lane >> 5;

  const float qscale = 0.17677669529663687f * 1.4426950408889634f;  // 1/sqrt(32)*log2e
  const __bf16* qrow = q + (size_t)(b * T_ + qt * 32 + lq) * D_ + h * 32 + hi * 8;
  bf16x8 qraw0 = *(const bf16x8*)(qrow);
  bf16x8 qraw1 = *(const bf16x8*)(qrow + 16);
  bf16x8 qf0, qf1;
  #pragma unroll
  for (int e = 0; e < 8; e++) {
    qf0[e] = (__bf16)((float)qraw0[e] * qscale);
    qf1[e] = (__bf16)((float)qraw1[e] * qscale);
  }

  const __bf16* kbase = k + (size_t)(b * T_) * D_ + h * 32 + hi * 8;
  const __bf16* vbase = vT + ((size_t)(b * H_ + h) * 32 + lq) * T_ + hi * 8;

  f32x16 acc;
  #pragma unroll
  for (int r = 0; r < 16; r++) acc[r] = 0.f;
  float l = 0.f;

  int kk = w * 512;
  bf16x8 kf0 = *(const bf16x8*)(kbase + (size_t)(kk + lq) * D_);
  bf16x8 kf1 = *(const bf16x8*)(kbase + (size_t)(kk + lq) * D_ + 16);
  bf16x8 vf0 = *(const bf16x8*)(vbase + kk);
  bf16x8 vf1 = *(const bf16x8*)(vbase + kk + 16);

  for (int it = 0; it < 16; it++) {
    __builtin_amdgcn_s_setprio(1);
    f32x16 s;
    #pragma unroll
    for (int r = 0; r < 16; r++) s[r] = -24.f;   // fixed-max bias via C-init
    s = __builtin_amdgcn_mfma_f32_32x32x16_bf16(kf0, qf0, s, 0, 0, 0);
    s = __builtin_amdgcn_mfma_f32_32x32x16_bf16(kf1, qf1, s, 0, 0, 0);
    __builtin_amdgcn_s_setprio(0);

    bf16x8 kn0, kn1, vn0, vn1;
    if (it < 15) {
      int k2 = kk + 32;
      kn0 = *(const bf16x8*)(kbase + (size_t)(k2 + lq) * D_);
      kn1 = *(const bf16x8*)(kbase + (size_t)(k2 + lq) * D_ + 16);
      vn0 = *(const bf16x8*)(vbase + k2);
      vn1 = *(const bf16x8*)(vbase + k2 + 16);
    }

    // fixed-max softmax + bf16 pack, all in-register (raw v_exp_f32).
    unsigned int aw[8];
    #pragma unroll
    for (int g = 0; g < 4; g++) {
      float p0 = __builtin_amdgcn_exp2f(s[g * 4 + 0]);
      float p1 = __builtin_amdgcn_exp2f(s[g * 4 + 1]);
      float p2 = __builtin_amdgcn_exp2f(s[g * 4 + 2]);
      float p3 = __builtin_amdgcn_exp2f(s[g * 4 + 3]);
      l += (p0 + p1) + (p2 + p3);
      unsigned int u01, u23;
      asm("v_cvt_pk_bf16_f32 %0, %1, %2" : "=v"(u01) : "v"(p0), "v"(p1));
      asm("v_cvt_pk_bf16_f32 %0, %1, %2" : "=v"(u23) : "v"(p2), "v"(p3));
      aw[g * 2] = u01; aw[g * 2 + 1] = u23;
    }
    // redistribute key halves across lane<32 / lane>=32 via permlane32_swap:
    // swap(A,B): A' = {A.lo, B.lo}, B' = {A.hi, B.hi}
    unsigned int a0 = aw[0], a2 = aw[2];
    asm volatile("v_permlane32_swap_b32 %0, %1" : "+v"(a0), "+v"(a2));
    unsigned int a1 = aw[1], a3 = aw[3];
    asm volatile("v_permlane32_swap_b32 %0, %1" : "+v"(a1), "+v"(a3));
    bf16x8 pw0 = __builtin_bit_cast(bf16x8, (u32x4v){a0, a1, a2, a3});
    unsigned int a4 = aw[4], a6 = aw[6];
    asm volatile("v_permlane32_swap_b32 %0, %1" : "+v"(a4), "+v"(a6));
    unsigned int a5 = aw[5], a7 = aw[7];
    asm volatile("v_permlane32_swap_b32 %0, %1" : "+v"(a5), "+v"(a7));
    bf16x8 pw1 = __builtin_bit_cast(bf16x8, (u32x4v){a4, a5, a6, a7});

    __builtin_amdgcn_s_setprio(1);
    acc = __builtin_amdgcn_mfma_f32_32x32x16_bf16(vf0, pw0, acc, 0, 0, 0);
    acc = __builtin_amdgcn_mfma_f32_32x32x16_bf16(vf1, pw1, acc, 0, 0, 0);
    __builtin_amdgcn_s_setprio(0);

    kf0 = kn0; kf1 = kn1; vf0 = vn0; vf1 = vn1;
    kk += 32;
  }

  // combine the two lane-halves' l per q-column
  l += __shfl_xor(l, 32, 64);

  if (w > 0) {
    float* mb = &mbuf[w - 1][lane][0];
    #pragma unroll
    for (int r = 0; r < 16; r++) mb[r] = acc[r];
    mb[16] = l;
  }
  __syncthreads();
  if (w == 0) {
    #pragma unroll
    for (int w2_ = 0; w2_ < 3; w2_++) {
      const float* mb = &mbuf[w2_][lane][0];
      #pragma unroll
      for (int r = 0; r < 16; r++) acc[r] += mb[r];
      l += mb[16];
    }
    float inv = 1.f / l;
    // lane holds O^T[dk][q=lq], dk = g*8 + 4*hi + j
    __bf16* crow = ctx + (size_t)(b * T_ + qt * 32 + lq) * D_ + h * 32 + hi * 4;
    #pragma unroll
    for (int g = 0; g < 4; g++) {
      bf16x4 o;
      #pragma unroll
      for (int j = 0; j < 4; j++) o[j] = (__bf16)(acc[g * 4 + j] * inv);
      *(bf16x4*)(crow + g * 8) = o;
    }
  }
}

// ---------------------------------------------------------------------------
// Fused Wo + LN + FFN (+ final LN), N-split: 4 waves/block, wave w owns cols
// [w*32, w*32+32) through all three GEMMs (residual stays in-register).
// ---------------------------------------------------------------------------
template <int LAST>
__global__ __launch_bounds__(256) void wo_ffn(
    const __bf16* __restrict__ ctxb, const __bf16* __restrict__ wto,
    const float* __restrict__ bo, const float* __restrict__ g1,
    const float* __restrict__ bt1, const __bf16* __restrict__ wt1,
    const float* __restrict__ b1, const __bf16* __restrict__ wt2,
    const float* __restrict__ b2, const float* __restrict__ g2,
    const float* __restrict__ bt2, __bf16* __restrict__ outb,
    float* __restrict__ outf)
{
  __shared__ __attribute__((aligned(16))) __bf16 tb0[16][128];
  __shared__ __attribute__((aligned(16))) __bf16 tb1[16][128];
  __shared__ float2 statb[16][4];

  int w = threadIdx.x >> 6, lane = threadIdx.x & 63;
  int m0 = blockIdx.x * 16;
  int lr = lane & 15, kg = lane >> 4;
  int swz = (lr & 7) << 3;

  const __bf16* arow = ctxb + (size_t)(m0 + lr) * D_ + kg * 8;
  bf16x8 af[4];
  #pragma unroll
  for (int ks = 0; ks < 4; ks++) af[ks] = *(const bf16x8*)(arow + ks * 32);

  f32x4 acc[2] = {{0, 0, 0, 0}, {0, 0, 0, 0}};
  #pragma unroll
  for (int i = 0; i < 2; i++) {
    const __bf16* wrow = wto + (size_t)((w * 2 + i) * 16 + lr) * D_ + kg * 8;
    #pragma unroll
    for (int ks = 0; ks < 4; ks++)
      acc[i] = __builtin_amdgcn_mfma_f32_16x16x32_bf16(af[ks], *(const bf16x8*)(wrow + ks * 32), acc[i], 0, 0, 0);
  }

  float xv[2][4];
  float s[4] = {0, 0, 0, 0}, s2[4] = {0, 0, 0, 0};
  #pragma unroll
  for (int i = 0; i < 2; i++) {
    float bcol = bo[(w * 2 + i) * 16 + lr];
    #pragma unroll
    for (int r = 0; r < 4; r++) {
      float y = acc[i][r] + bcol;
      xv[i][r] = y; s[r] += y; s2[r] += y * y;
    }
  }
  #pragma unroll
  for (int r = 0; r < 4; r++)
    for (int mk = 1; mk < 16; mk <<= 1) {
      s[r] += __shfl_xor(s[r], mk, 64);
      s2[r] += __shfl_xor(s2[r], mk, 64);
    }
  if (lr == 0) {
    #pragma unroll
    for (int r = 0; r < 4; r++) statb[kg * 4 + r][w] = make_float2(s[r], s2[r]);
  }
  __syncthreads();
  float mu_[4], rstd_[4];
  #pragma unroll
  for (int r = 0; r < 4; r++) {
    int row = kg * 4 + r;
    float ss = 0.f, ss2 = 0.f;
    #pragma unroll
    for (int w2 = 0; w2 < 4; w2++) {
      float2 t = statb[row][w2];
      ss += t.x; ss2 += t.y;
    }
    mu_[r] = ss * (1.f / D_);
    float var = ss2 * (1.f / D_) - mu_[r] * mu_[r];
    rstd_[r] = rsqrtf(var + 1e-3f);
  }
  float hres[2][4];
  #pragma unroll
  for (int i = 0; i < 2; i++) {
    int col = (w * 2 + i) * 16 + lr;
    float gc = g1[col], bc = bt1[col];
    #pragma unroll
    for (int r = 0; r < 4; r++) {
      float y = (xv[i][r] - mu_[r]) * rstd_[r] * gc + bc;
      hres[i][r] = y;
      int row = kg * 4 + r;
      tb0[row][col ^ ((row & 7) << 3)] = (__bf16)y;
    }
  }
  __syncthreads();

  bf16x8 a2[4];
  #pragma unroll
  for (int ks = 0; ks < 4; ks++)
    a2[ks] = *(const bf16x8*)(&tb0[lr][(ks * 32 + kg * 8) ^ swz]);
  f32x4 acc2[2] = {{0, 0, 0, 0}, {0, 0, 0, 0}};
  #pragma unroll
  for (int i = 0; i < 2; i++) {
    const __bf16* wrow = wt1 + (size_t)((w * 2 + i) * 16 + lr) * D_ + kg * 8;
    #pragma unroll
    for (int ks = 0; ks < 4; ks++)
      acc2[i] = __builtin_amdgcn_mfma_f32_16x16x32_bf16(a2[ks], *(const bf16x8*)(wrow + ks * 32), acc2[i], 0, 0, 0);
  }
  #pragma unroll
  for (int i = 0; i < 2; i++) {
    float bcol = b1[(w * 2 + i) * 16 + lr];
    int col = (w * 2 + i) * 16 + lr;
    #pragma unroll
    for (int r = 0; r < 4; r++) {
      int row = kg * 4 + r;
      tb1[row][col ^ ((row & 7) << 3)] = (__bf16)fmaxf(acc2[i][r] + bcol, 0.f);
    }
  }
  __syncthreads();

  bf16x8 a3[4];
  #pragma unroll
  for (int ks = 0; ks < 4; ks++)
    a3[ks] = *(const bf16x8*)(&tb1[lr][(ks * 32 + kg * 8) ^ swz]);
  f32x4 acc3[2] = {{0, 0, 0, 0}, {0, 0, 0, 0}};
  #pragma unroll
  for (int i = 0; i < 2; i++) {
    const __bf16* wrow = wt2 + (size_t)((w * 2 + i) * 16 + lr) * D_ + kg * 8;
    #pragma unroll
    for (int ks = 0; ks < 4; ks++)
      acc3[i] = __builtin_amdgcn_mfma_f32_16x16x32_bf16(a3[ks], *(const bf16x8*)(wrow + ks * 32), acc3[i], 0, 0, 0);
  }

  if constexpr (LAST) {
    float yv[2][4];
    float t[4] = {0, 0, 0, 0}, t2[4] = {0, 0, 0, 0};
    #pragma unroll
    for (int i = 0; i < 2; i++) {
      float bcol = b2[(w * 2 + i) * 16 + lr];
      #pragma unroll
      for (int r = 0; r < 4; r++) {
        float y = acc3[i][r] + bcol + hres[i][r];
        yv[i][r] = y; t[r] += y; t2[r] += y * y;
      }
    }
    #pragma unroll
    for (int r = 0; r < 4; r++)
      for (int mk = 1; mk < 16; mk <<= 1) {
        t[r] += __shfl_xor(t[r], mk, 64);
        t2[r] += __shfl_xor(t2[r], mk, 64);
      }
    __syncthreads();
    if (lr == 0) {
      #pragma unroll
      for (int r = 0; r < 4; r++) statb[kg * 4 + r][w] = make_float2(t[r], t2[r]);
    }
    __syncthreads();
    #pragma unroll
    for (int r = 0; r < 4; r++) {
      int row = kg * 4 + r;
      float ss = 0.f, ss2 = 0.f;
      #pragma unroll
      for (int w2 = 0; w2 < 4; w2++) {
        float2 tt = statb[row][w2];
        ss += tt.x; ss2 += tt.y;
      }
      float mu = ss * (1.f / D_);
      float var = ss2 * (1.f / D_) - mu * mu;
      float rstd = rsqrtf(var + 1e-3f);
      #pragma unroll
      for (int i = 0; i < 2; i++) {
        int col = (w * 2 + i) * 16 + lr;
        outf[(size_t)(m0 + row) * D_ + col] =
            (yv[i][r] - mu) * rstd * g2[col] + bt2[col];
      }
    }
  } else {
    #pragma unroll
    for (int i = 0; i < 2; i++) {
      int col = (w * 2 + i) * 16 + lr;
      float bcol = b2[col];
      #pragma unroll
      for (int r = 0; r < 4; r++)
        outb[(size_t)(m0 + kg * 4 + r) * D_ + col] =
            (__bf16)(acc3[i][r] + bcol + hres[i][r]);
    }
  }
}

// ---------------------------------------------------------------------------
extern "C" void kernel_launch(void* const* d_in, const int* in_sizes, int n_in,
                              void* d_out, int out_size, void* d_ws, size_t ws_size,
                              hipStream_t stream)
{
  const float* inputs = (const float*)d_in[0];
  const float* Wq = (const float*)d_in[1];
  const float* bq = (const float*)d_in[2];
  const float* Wk = (const float*)d_in[3];
  const float* bk = (const float*)d_in[4];
  const float* Wv = (const float*)d_in[5];
  const float* bv = (const float*)d_in[6];
  const float* Wo = (const float*)d_in[7];
  const float* bo = (const float*)d_in[8];
  const float* W1 = (const float*)d_in[9];
  const float* b1 = (const float*)d_in[10];
  const float* W2 = (const float*)d_in[11];
  const float* b2 = (const float*)d_in[12];
  const float* ln_g = (const float*)d_in[13];
  const float* ln_b = (const float*)d_in[14];
  float* out = (float*)d_out;

  char* ws = (char*)d_ws;
  size_t off = 0;
  auto alloc = [&](size_t bytes) {
    void* p = ws + off;
    off = (off + bytes + 255) & ~(size_t)255;
    return p;
  };
  const size_t ACT = (size_t)8192 * 128 * sizeof(__bf16);  // 2 MB
  __bf16* wt   = (__bf16*)alloc((size_t)6 * NB_ * 128 * 128 * sizeof(__bf16));
  __bf16* hbuf = (__bf16*)alloc(ACT);
  __bf16* qb   = (__bf16*)alloc(ACT);
  __bf16* kb   = (__bf16*)alloc(ACT);
  __bf16* vb   = (__bf16*)alloc(ACT);
  __bf16* ctxb = (__bf16*)alloc(ACT);

  prep_weights<<<768, 256, 0, stream>>>(Wq, Wk, Wv, Wo, W1, W2, wt);
  posadd<<<2048, 256, 0, stream>>>(inputs, hbuf);

  for (int i = 0; i < NB_; i++) {
    const __bf16* wtq = wt + (size_t)(0 * NB_ + i) * 16384;
    const __bf16* wtk = wt + (size_t)(1 * NB_ + i) * 16384;
    const __bf16* wtv = wt + (size_t)(2 * NB_ + i) * 16384;
    const __bf16* wto = wt + (size_t)(3 * NB_ + i) * 16384;
    const __bf16* wt1 = wt + (size_t)(4 * NB_ + i) * 16384;
    const __bf16* wt2 = wt + (size_t)(5 * NB_ + i) * 16384;

    lnqkv<<<512, 256, 0, stream>>>(hbuf, wtq, wtk, wtv,
                                   bq + i * 128, bk + i * 128, bv + i * 128,
                                   ln_g + (size_t)(2 * i) * 128, ln_b + (size_t)(2 * i) * 128,
                                   qb, kb, vb);
    attn6<<<1024, 256, 0, stream>>>(qb, kb, vb, ctxb);
    if (i == 0) {
      wo_ffn<0><<<512, 256, 0, stream>>>(ctxb, wto, bo + i * 128,
                                         ln_g + 1 * 128, ln_b + 1 * 128,
                                         wt1, b1 + i * 128, wt2, b2 + i * 128,
                                         nullptr, nullptr, hbuf, nullptr);
    } else {
      wo_ffn<1><<<512, 256, 0, stream>>>(ctxb, wto, bo + i * 128,
                                         ln_g + 3 * 128, ln_b + 3 * 128,
                                         wt1, b1 + i * 128, wt2, b2 + i * 128,
                                         ln_g + 3 * 128, ln_b + 3 * 128,
                                         nullptr, out);
    }
  }
}

// Round 10
// 157.085 us; speedup vs baseline: 1.7656x; 1.2648x over previous
//
#include <hip/hip_runtime.h>
#include <hip/hip_bf16.h>

typedef __bf16 bf16x8 __attribute__((ext_vector_type(8)));
typedef __bf16 bf16x4 __attribute__((ext_vector_type(4)));
typedef float f32x4 __attribute__((ext_vector_type(4)));
typedef float f32x16 __attribute__((ext_vector_type(16)));
typedef unsigned int u32x4v __attribute__((ext_vector_type(4)));

#define D_ 128
#define T_ 2048
#define B_ 4
#define H_ 4
#define NB_ 2

// ===========================================================================
// Fragment-packed layouts (bf16, all frag loads are `base + lane*8`, 1KB):
//  wp[(j*NB+i)*32 + nt*4 + ks][lane][e]  = W[k=ks*32+(lane>>4)*8+e][n=nt*16+(lane&15)]
//  hp[(row>>4)*4 + ks][lane][e]          = A[row16+(lane&15)][ks*32+(lane>>4)*8+e]
//  cp[(qrow>>4)*4 + h][lane][e]          = ctx[...same A-frag pattern...]
//  qp[((b*64+qt)*4+h)*2+fs][lane][e]     = Q[b,qt*32+(lane&31)][h*32+fs*16+(lane>>5)*8+e]
//  kp[((b*4+h)*64+kt)*2+fs][lane][e]     = K[b,kt*32+(lane&31)][h*32+fs*16+(lane>>5)*8+e]
//  vp[((b*4+h)*64+tt)*2+fs][lane][e]     = V[b,tt*32+fs*16+(lane>>5)*8+e][h*32+(lane&31)]
// ===========================================================================

// ---------------------------------------------------------------------------
// Weight prep: fp32 [NB][128][128] -> frag-packed bf16 wp.
// ---------------------------------------------------------------------------
__global__ __launch_bounds__(256) void prep_weights(
    const float* __restrict__ Wq, const float* __restrict__ Wk,
    const float* __restrict__ Wv, const float* __restrict__ Wo,
    const float* __restrict__ W1, const float* __restrict__ W2,
    __bf16* __restrict__ wp)
{
  int tid = blockIdx.x * 256 + threadIdx.x;   // < 6*NB*8*4*64*8 = 196608
  int e    = tid & 7;
  int lane = (tid >> 3) & 63;
  int ks   = (tid >> 9) & 3;
  int nt   = (tid >> 11) & 7;
  int i    = (tid >> 14) & (NB_ - 1);
  int j    = tid >> 15;
  int k = ks * 32 + (lane >> 4) * 8 + e;
  int n = nt * 16 + (lane & 15);
  const float* srcs[6] = {Wq, Wk, Wv, Wo, W1, W2};
  wp[tid] = (__bf16)srcs[j][i * 16384 + k * 128 + n];
}

// ---------------------------------------------------------------------------
// h0 = bf16(inputs + pos_encoding), written in hp (A-frag-packed) layout.
// ---------------------------------------------------------------------------
__global__ __launch_bounds__(256) void posadd(
    const float* __restrict__ x, __bf16* __restrict__ hp)
{
  int w = threadIdx.x >> 6, lane = threadIdx.x & 63;
  int row = blockIdx.x * 4 + w;
  int t = row & (T_ - 1);
  #pragma unroll
  for (int e = 0; e < 2; e++) {
    int c = lane * 2 + e;
    float arg = (float)t * exp2f(-0.20762050593045952f * (float)c);
    float pe = (c & 1) ? cosf(arg) : sinf(arg);
    float v = x[row * D_ + c] + pe;
    size_t idx = ((size_t)(row >> 4) * 4 + (c >> 5)) * 512 +
                 ((row & 15) + 16 * ((c >> 3) & 3)) * 8 + (c & 7);
    hp[idx] = (__bf16)v;
  }
}

// ---------------------------------------------------------------------------
// Fused LN + QKV. 4 waves/block, wave w = head w (cols w*32..w*32+32).
// A-frags loaded packed from hp; weights packed from wp; LN in-register.
// Outputs written in qp/kp/vp packed layouts (16B-run scatter stores).
// ---------------------------------------------------------------------------
__global__ __launch_bounds__(256) void lnqkv(
    const __bf16* __restrict__ hp, const __bf16* __restrict__ wpq,
    const __bf16* __restrict__ wpk, const __bf16* __restrict__ wpv,
    const float* __restrict__ bq, const float* __restrict__ bk,
    const float* __restrict__ bv, const float* __restrict__ g,
    const float* __restrict__ beta,
    __bf16* __restrict__ qp, __bf16* __restrict__ kp, __bf16* __restrict__ vp)
{
  int w = threadIdx.x >> 6, lane = threadIdx.x & 63;
  int m0 = blockIdx.x * 16;
  int lr = lane & 15, kg = lane >> 4;

  bf16x8 araw[4];
  #pragma unroll
  for (int ks = 0; ks < 4; ks++)
    araw[ks] = *(const bf16x8*)(hp + ((size_t)blockIdx.x * 4 + ks) * 512 + lane * 8);

  float s = 0.f, s2 = 0.f;
  #pragma unroll
  for (int ks = 0; ks < 4; ks++)
    #pragma unroll
    for (int e = 0; e < 8; e++) {
      float x = (float)araw[ks][e];
      s += x; s2 += x * x;
    }
  s += __shfl_xor(s, 16, 64);  s2 += __shfl_xor(s2, 16, 64);
  s += __shfl_xor(s, 32, 64);  s2 += __shfl_xor(s2, 32, 64);
  float mu = s * (1.f / D_);
  float var = s2 * (1.f / D_) - mu * mu;
  float rstd = rsqrtf(var + 1e-3f);

  bf16x8 af[4];
  #pragma unroll
  for (int ks = 0; ks < 4; ks++) {
    int c0 = ks * 32 + kg * 8;
    float4 g0 = *(const float4*)(g + c0), g1 = *(const float4*)(g + c0 + 4);
    float4 q0 = *(const float4*)(beta + c0), q1 = *(const float4*)(beta + c0 + 4);
    const float* gp[2] = {&g0.x, &g1.x};
    const float* bp[2] = {&q0.x, &q1.x};
    #pragma unroll
    for (int e = 0; e < 8; e++)
      af[ks][e] = (__bf16)(((float)araw[ks][e] - mu) * rstd * gp[e >> 2][e & 3] + bp[e >> 2][e & 3]);
  }

  #pragma unroll
  for (int i = 0; i < 2; i++) {
    int nt = w * 2 + i;
    const __bf16* wq = wpq + (size_t)(nt * 4) * 512 + lane * 8;
    const __bf16* wk = wpk + (size_t)(nt * 4) * 512 + lane * 8;
    const __bf16* wv = wpv + (size_t)(nt * 4) * 512 + lane * 8;
    f32x4 aq = {0, 0, 0, 0}, ak = {0, 0, 0, 0}, av = {0, 0, 0, 0};
    #pragma unroll
    for (int ks = 0; ks < 4; ks++) {
      aq = __builtin_amdgcn_mfma_f32_16x16x32_bf16(af[ks], *(const bf16x8*)(wq + ks * 512), aq, 0, 0, 0);
      ak = __builtin_amdgcn_mfma_f32_16x16x32_bf16(af[ks], *(const bf16x8*)(wk + ks * 512), ak, 0, 0, 0);
      av = __builtin_amdgcn_mfma_f32_16x16x32_bf16(af[ks], *(const bf16x8*)(wv + ks * 512), av, 0, 0, 0);
    }
    int col = nt * 16 + lr;
    float bqc = bq[col], bkc = bk[col], bvc = bv[col];
    int dk = i * 16 + lr;               // head-local col
    int hi8 = (lr >> 3) & 1;            // dk>>3 within 16-block
    #pragma unroll
    for (int r = 0; r < 4; r++) {
      int row = m0 + kg * 4 + r;
      int bb = row >> 11, tt = row & (T_ - 1);
      // Q packed
      size_t qidx = ((((size_t)(bb * 64 + (tt >> 5)) * 4 + w) * 2 + i) * 512) +
                    ((tt & 31) + 32 * hi8) * 8 + (lr & 7);
      qp[qidx] = (__bf16)(aq[r] + bqc);
      // K packed
      size_t kidx = ((((size_t)(bb * 4 + w) * 64 + (tt >> 5)) * 2 + i) * 512) +
                    ((tt & 31) + 32 * hi8) * 8 + (lr & 7);
      kp[kidx] = (__bf16)(ak[r] + bkc);
      // V packed
      size_t vidx = ((((size_t)(bb * 4 + w) * 64 + (tt >> 5)) * 2 + ((tt >> 4) & 1)) * 512) +
                    (dk + 32 * ((tt >> 3) & 1)) * 8 + (tt & 7);
      vp[vidx] = (__bf16)(av[r] + bvc);
    }
  }
}

// ---------------------------------------------------------------------------
// Flash attention v7: 32x32 swapped structure, all loads frag-packed (1KB
// contiguous, zero gathers, zero LDS in loop). Fixed-max softmax via C=-24,
// raw v_exp_f32, permlane32_swap P redistribution (validated round 8/9).
// 4-way KV split, merged once. XCD swizzle via bh = blk&15. Output -> cp.
// ---------------------------------------------------------------------------
__global__ __launch_bounds__(256) void attn7(
    const __bf16* __restrict__ qp, const __bf16* __restrict__ kp,
    const __bf16* __restrict__ vp, __bf16* __restrict__ cp)
{
  __shared__ float mbuf[3][64][17];

  int w = threadIdx.x >> 6, lane = threadIdx.x & 63;
  int bh = blockIdx.x & 15, qt = blockIdx.x >> 4;   // qt 0..63
  int b = bh >> 2, h = bh & 3;
  int lq = lane & 31, hi = lane >> 5;

  const float qscale = 0.17677669529663687f * 1.4426950408889634f;  // 1/sqrt(32)*log2e
  const __bf16* qbase = qp + (((size_t)(b * 64 + qt) * 4 + h) * 2) * 512 + lane * 8;
  bf16x8 qraw0 = *(const bf16x8*)(qbase);
  bf16x8 qraw1 = *(const bf16x8*)(qbase + 512);
  bf16x8 qf0, qf1;
  #pragma unroll
  for (int e = 0; e < 8; e++) {
    qf0[e] = (__bf16)((float)qraw0[e] * qscale);
    qf1[e] = (__bf16)((float)qraw1[e] * qscale);
  }

  const __bf16* kbase = kp + ((size_t)(b * 4 + h) * 64) * 1024 + lane * 8;
  const __bf16* vbase = vp + ((size_t)(b * 4 + h) * 64) * 1024 + lane * 8;

  f32x16 acc;
  #pragma unroll
  for (int r = 0; r < 16; r++) acc[r] = 0.f;
  float l = 0.f;

  int kt = w * 16;
  bf16x8 kf0 = *(const bf16x8*)(kbase + (size_t)kt * 1024);
  bf16x8 kf1 = *(const bf16x8*)(kbase + (size_t)kt * 1024 + 512);
  bf16x8 vf0 = *(const bf16x8*)(vbase + (size_t)kt * 1024);
  bf16x8 vf1 = *(const bf16x8*)(vbase + (size_t)kt * 1024 + 512);

  for (int it = 0; it < 16; it++) {
    __builtin_amdgcn_s_setprio(1);
    f32x16 s;
    #pragma unroll
    for (int r = 0; r < 16; r++) s[r] = -24.f;   // fixed-max bias via C-init
    s = __builtin_amdgcn_mfma_f32_32x32x16_bf16(kf0, qf0, s, 0, 0, 0);
    s = __builtin_amdgcn_mfma_f32_32x32x16_bf16(kf1, qf1, s, 0, 0, 0);
    __builtin_amdgcn_s_setprio(0);

    bf16x8 kn0, kn1, vn0, vn1;
    if (it < 15) {
      size_t nb = (size_t)(kt + 1) * 1024;
      kn0 = *(const bf16x8*)(kbase + nb);
      kn1 = *(const bf16x8*)(kbase + nb + 512);
      vn0 = *(const bf16x8*)(vbase + nb);
      vn1 = *(const bf16x8*)(vbase + nb + 512);
    }

    // fixed-max softmax + bf16 pack, all in-register (raw v_exp_f32).
    unsigned int aw[8];
    #pragma unroll
    for (int g = 0; g < 4; g++) {
      float p0 = __builtin_amdgcn_exp2f(s[g * 4 + 0]);
      float p1 = __builtin_amdgcn_exp2f(s[g * 4 + 1]);
      float p2 = __builtin_amdgcn_exp2f(s[g * 4 + 2]);
      float p3 = __builtin_amdgcn_exp2f(s[g * 4 + 3]);
      l += (p0 + p1) + (p2 + p3);
      unsigned int u01, u23;
      asm("v_cvt_pk_bf16_f32 %0, %1, %2" : "=v"(u01) : "v"(p0), "v"(p1));
      asm("v_cvt_pk_bf16_f32 %0, %1, %2" : "=v"(u23) : "v"(p2), "v"(p3));
      aw[g * 2] = u01; aw[g * 2 + 1] = u23;
    }
    // redistribute key halves across lane<32 / lane>=32 via permlane32_swap
    unsigned int a0 = aw[0], a2 = aw[2];
    asm volatile("v_permlane32_swap_b32 %0, %1" : "+v"(a0), "+v"(a2));
    unsigned int a1 = aw[1], a3 = aw[3];
    asm volatile("v_permlane32_swap_b32 %0, %1" : "+v"(a1), "+v"(a3));
    bf16x8 pw0 = __builtin_bit_cast(bf16x8, (u32x4v){a0, a1, a2, a3});
    unsigned int a4 = aw[4], a6 = aw[6];
    asm volatile("v_permlane32_swap_b32 %0, %1" : "+v"(a4), "+v"(a6));
    unsigned int a5 = aw[5], a7 = aw[7];
    asm volatile("v_permlane32_swap_b32 %0, %1" : "+v"(a5), "+v"(a7));
    bf16x8 pw1 = __builtin_bit_cast(bf16x8, (u32x4v){a4, a5, a6, a7});

    __builtin_amdgcn_s_setprio(1);
    acc = __builtin_amdgcn_mfma_f32_32x32x16_bf16(vf0, pw0, acc, 0, 0, 0);
    acc = __builtin_amdgcn_mfma_f32_32x32x16_bf16(vf1, pw1, acc, 0, 0, 0);
    __builtin_amdgcn_s_setprio(0);

    kf0 = kn0; kf1 = kn1; vf0 = vn0; vf1 = vn1;
    kt += 1;
  }

  // combine the two lane-halves' l per q-column
  l += __shfl_xor(l, 32, 64);

  if (w > 0) {
    float* mb = &mbuf[w - 1][lane][0];
    #pragma unroll
    for (int r = 0; r < 16; r++) mb[r] = acc[r];
    mb[16] = l;
  }
  __syncthreads();
  if (w == 0) {
    #pragma unroll
    for (int w2_ = 0; w2_ < 3; w2_++) {
      const float* mb = &mbuf[w2_][lane][0];
      #pragma unroll
      for (int r = 0; r < 16; r++) acc[r] += mb[r];
      l += mb[16];
    }
    float inv = 1.f / l;
    // lane holds O^T[dk = g*8+4*hi+j][q = qt*32+lq]; write A-frag-packed cp
    __bf16* cbase = cp + ((size_t)(b * 128 + qt * 2 + (lq >> 4)) * 4 + h) * 512 + 4 * hi;
    #pragma unroll
    for (int g = 0; g < 4; g++) {
      bf16x4 o;
      #pragma unroll
      for (int j = 0; j < 4; j++) o[j] = (__bf16)(acc[g * 4 + j] * inv);
      *(bf16x4*)(cbase + ((lq & 15) + 16 * g) * 8) = o;
    }
  }
}

// ---------------------------------------------------------------------------
// Fused Wo + LN + FFN (+ final LN). A-frags packed from cp; weights packed.
// Internal LDS transposes (tb0/tb1) unchanged. LAST=0 -> hp packed out;
// LAST=1 -> final LN -> fp32 row-major out.
// ---------------------------------------------------------------------------
template <int LAST>
__global__ __launch_bounds__(256) void wo_ffn(
    const __bf16* __restrict__ cp, const __bf16* __restrict__ wpo,
    const float* __restrict__ bo, const float* __restrict__ g1,
    const float* __restrict__ bt1, const __bf16* __restrict__ wp1,
    const float* __restrict__ b1, const __bf16* __restrict__ wp2,
    const float* __restrict__ b2, const float* __restrict__ g2,
    const float* __restrict__ bt2, __bf16* __restrict__ hp,
    float* __restrict__ outf)
{
  __shared__ __attribute__((aligned(16))) __bf16 tb0[16][128];
  __shared__ __attribute__((aligned(16))) __bf16 tb1[16][128];
  __shared__ float2 statb[16][4];

  int w = threadIdx.x >> 6, lane = threadIdx.x & 63;
  int m0 = blockIdx.x * 16;
  int lr = lane & 15, kg = lane >> 4;
  int swz = (lr & 7) << 3;

  bf16x8 af[4];
  #pragma unroll
  for (int ks = 0; ks < 4; ks++)
    af[ks] = *(const bf16x8*)(cp + ((size_t)blockIdx.x * 4 + ks) * 512 + lane * 8);

  f32x4 acc[2] = {{0, 0, 0, 0}, {0, 0, 0, 0}};
  #pragma unroll
  for (int i = 0; i < 2; i++) {
    const __bf16* wrow = wpo + (size_t)((w * 2 + i) * 4) * 512 + lane * 8;
    #pragma unroll
    for (int ks = 0; ks < 4; ks++)
      acc[i] = __builtin_amdgcn_mfma_f32_16x16x32_bf16(af[ks], *(const bf16x8*)(wrow + ks * 512), acc[i], 0, 0, 0);
  }

  float xv[2][4];
  float s[4] = {0, 0, 0, 0}, s2[4] = {0, 0, 0, 0};
  #pragma unroll
  for (int i = 0; i < 2; i++) {
    float bcol = bo[(w * 2 + i) * 16 + lr];
    #pragma unroll
    for (int r = 0; r < 4; r++) {
      float y = acc[i][r] + bcol;
      xv[i][r] = y; s[r] += y; s2[r] += y * y;
    }
  }
  #pragma unroll
  for (int r = 0; r < 4; r++)
    for (int mk = 1; mk < 16; mk <<= 1) {
      s[r] += __shfl_xor(s[r], mk, 64);
      s2[r] += __shfl_xor(s2[r], mk, 64);
    }
  if (lr == 0) {
    #pragma unroll
    for (int r = 0; r < 4; r++) statb[kg * 4 + r][w] = make_float2(s[r], s2[r]);
  }
  __syncthreads();
  float mu_[4], rstd_[4];
  #pragma unroll
  for (int r = 0; r < 4; r++) {
    int row = kg * 4 + r;
    float ss = 0.f, ss2 = 0.f;
    #pragma unroll
    for (int w2 = 0; w2 < 4; w2++) {
      float2 t = statb[row][w2];
      ss += t.x; ss2 += t.y;
    }
    mu_[r] = ss * (1.f / D_);
    float var = ss2 * (1.f / D_) - mu_[r] * mu_[r];
    rstd_[r] = rsqrtf(var + 1e-3f);
  }
  float hres[2][4];
  #pragma unroll
  for (int i = 0; i < 2; i++) {
    int col = (w * 2 + i) * 16 + lr;
    float gc = g1[col], bc = bt1[col];
    #pragma unroll
    for (int r = 0; r < 4; r++) {
      float y = (xv[i][r] - mu_[r]) * rstd_[r] * gc + bc;
      hres[i][r] = y;
      int row = kg * 4 + r;
      tb0[row][col ^ ((row & 7) << 3)] = (__bf16)y;
    }
  }
  __syncthreads();

  bf16x8 a2[4];
  #pragma unroll
  for (int ks = 0; ks < 4; ks++)
    a2[ks] = *(const bf16x8*)(&tb0[lr][(ks * 32 + kg * 8) ^ swz]);
  f32x4 acc2[2] = {{0, 0, 0, 0}, {0, 0, 0, 0}};
  #pragma unroll
  for (int i = 0; i < 2; i++) {
    const __bf16* wrow = wp1 + (size_t)((w * 2 + i) * 4) * 512 + lane * 8;
    #pragma unroll
    for (int ks = 0; ks < 4; ks++)
      acc2[i] = __builtin_amdgcn_mfma_f32_16x16x32_bf16(a2[ks], *(const bf16x8*)(wrow + ks * 512), acc2[i], 0, 0, 0);
  }
  #pragma unroll
  for (int i = 0; i < 2; i++) {
    float bcol = b1[(w * 2 + i) * 16 + lr];
    int col = (w * 2 + i) * 16 + lr;
    #pragma unroll
    for (int r = 0; r < 4; r++) {
      int row = kg * 4 + r;
      tb1[row][col ^ ((row & 7) << 3)] = (__bf16)fmaxf(acc2[i][r] + bcol, 0.f);
    }
  }
  __syncthreads();

  bf16x8 a3[4];
  #pragma unroll
  for (int ks = 0; ks < 4; ks++)
    a3[ks] = *(const bf16x8*)(&tb1[lr][(ks * 32 + kg * 8) ^ swz]);
  f32x4 acc3[2] = {{0, 0, 0, 0}, {0, 0, 0, 0}};
  #pragma unroll
  for (int i = 0; i < 2; i++) {
    const __bf16* wrow = wp2 + (size_t)((w * 2 + i) * 4) * 512 + lane * 8;
    #pragma unroll
    for (int ks = 0; ks < 4; ks++)
      acc3[i] = __builtin_amdgcn_mfma_f32_16x16x32_bf16(a3[ks], *(const bf16x8*)(wrow + ks * 512), acc3[i], 0, 0, 0);
  }

  if constexpr (LAST) {
    float yv[2][4];
    float t[4] = {0, 0, 0, 0}, t2[4] = {0, 0, 0, 0};
    #pragma unroll
    for (int i = 0; i < 2; i++) {
      float bcol = b2[(w * 2 + i) * 16 + lr];
      #pragma unroll
      for (int r = 0; r < 4; r++) {
        float y = acc3[i][r] + bcol + hres[i][r];
        yv[i][r] = y; t[r] += y; t2[r] += y * y;
      }
    }
    #pragma unroll
    for (int r = 0; r < 4; r++)
      for (int mk = 1; mk < 16; mk <<= 1) {
        t[r] += __shfl_xor(t[r], mk, 64);
        t2[r] += __shfl_xor(t2[r], mk, 64);
      }
    __syncthreads();
    if (lr == 0) {
      #pragma unroll
      for (int r = 0; r < 4; r++) statb[kg * 4 + r][w] = make_float2(t[r], t2[r]);
    }
    __syncthreads();
    #pragma unroll
    for (int r = 0; r < 4; r++) {
      int row = kg * 4 + r;
      float ss = 0.f, ss2 = 0.f;
      #pragma unroll
      for (int w2 = 0; w2 < 4; w2++) {
        float2 tt = statb[row][w2];
        ss += tt.x; ss2 += tt.y;
      }
      float mu = ss * (1.f / D_);
      float var = ss2 * (1.f / D_) - mu * mu;
      float rstd = rsqrtf(var + 1e-3f);
      #pragma unroll
      for (int i = 0; i < 2; i++) {
        int col = (w * 2 + i) * 16 + lr;
        outf[(size_t)(m0 + row) * D_ + col] =
            (yv[i][r] - mu) * rstd * g2[col] + bt2[col];
      }
    }
  } else {
    // write hp packed (A-frag layout) for the next layer's lnqkv
    #pragma unroll
    for (int i = 0; i < 2; i++) {
      int col = (w * 2 + i) * 16 + lr;
      float bcol = b2[col];
      size_t base = ((size_t)blockIdx.x * 4 + w) * 512 +
                    (size_t)16 * ((2 * i + (lr >> 3)) & 3) * 8 + (lr & 7);
      #pragma unroll
      for (int r = 0; r < 4; r++)
        hp[base + (kg * 4 + r) * 8] = (__bf16)(acc3[i][r] + bcol + hres[i][r]);
    }
  }
}

// ---------------------------------------------------------------------------
extern "C" void kernel_launch(void* const* d_in, const int* in_sizes, int n_in,
                              void* d_out, int out_size, void* d_ws, size_t ws_size,
                              hipStream_t stream)
{
  const float* inputs = (const float*)d_in[0];
  const float* Wq = (const float*)d_in[1];
  const float* bq = (const float*)d_in[2];
  const float* Wk = (const float*)d_in[3];
  const float* bk = (const float*)d_in[4];
  const float* Wv = (const float*)d_in[5];
  const float* bv = (const float*)d_in[6];
  const float* Wo = (const float*)d_in[7];
  const float* bo = (const float*)d_in[8];
  const float* W1 = (const float*)d_in[9];
  const float* b1 = (const float*)d_in[10];
  const float* W2 = (const float*)d_in[11];
  const float* b2 = (const float*)d_in[12];
  const float* ln_g = (const float*)d_in[13];
  const float* ln_b = (const float*)d_in[14];
  float* out = (float*)d_out;

  char* ws = (char*)d_ws;
  size_t off = 0;
  auto alloc = [&](size_t bytes) {
    void* p = ws + off;
    off = (off + bytes + 255) & ~(size_t)255;
    return p;
  };
  const size_t ACT = (size_t)8192 * 128 * sizeof(__bf16);  // 2 MB
  __bf16* wp = (__bf16*)alloc((size_t)6 * NB_ * 16384 * sizeof(__bf16));
  __bf16* hp = (__bf16*)alloc(ACT);
  __bf16* qp = (__bf16*)alloc(ACT);
  __bf16* kp = (__bf16*)alloc(ACT);
  __bf16* vp = (__bf16*)alloc(ACT);
  __bf16* cb = (__bf16*)alloc(ACT);

  prep_weights<<<768, 256, 0, stream>>>(Wq, Wk, Wv, Wo, W1, W2, wp);
  posadd<<<2048, 256, 0, stream>>>(inputs, hp);

  for (int i = 0; i < NB_; i++) {
    const __bf16* wpq = wp + (size_t)(0 * NB_ + i) * 16384;
    const __bf16* wpk = wp + (size_t)(1 * NB_ + i) * 16384;
    const __bf16* wpv = wp + (size_t)(2 * NB_ + i) * 16384;
    const __bf16* wpo = wp + (size_t)(3 * NB_ + i) * 16384;
    const __bf16* wp1 = wp + (size_t)(4 * NB_ + i) * 16384;
    const __bf16* wp2 = wp + (size_t)(5 * NB_ + i) * 16384;

    lnqkv<<<512, 256, 0, stream>>>(hp, wpq, wpk, wpv,
                                   bq + i * 128, bk + i * 128, bv + i * 128,
                                   ln_g + (size_t)(2 * i) * 128, ln_b + (size_t)(2 * i) * 128,
                                   qp, kp, vp);
    attn7<<<1024, 256, 0, stream>>>(qp, kp, vp, cb);
    if (i == 0) {
      wo_ffn<0><<<512, 256, 0, stream>>>(cb, wpo, bo + i * 128,
                                         ln_g + 1 * 128, ln_b + 1 * 128,
                                         wp1, b1 + i * 128, wp2, b2 + i * 128,
                                         nullptr, nullptr, hp, nullptr);
    } else {
      wo_ffn<1><<<512, 256, 0, stream>>>(cb, wpo, bo + i * 128,
                                         ln_g + 3 * 128, ln_b + 3 * 128,
                                         wp1, b1 + i * 128, wp2, b2 + i * 128,
                                         ln_g + 3 * 128, ln_b + 3 * 128,
                                         nullptr, out);
    }
  }
}

// Round 11
// 148.332 us; speedup vs baseline: 1.8697x; 1.0590x over previous
//
#include <hip/hip_runtime.h>
#include <hip/hip_bf16.h>

typedef __bf16 bf16x8 __attribute__((ext_vector_type(8)));
typedef __bf16 bf16x4 __attribute__((ext_vector_type(4)));
typedef float f32x4 __attribute__((ext_vector_type(4)));
typedef float f32x16 __attribute__((ext_vector_type(16)));
typedef unsigned int u32x4v __attribute__((ext_vector_type(4)));

#define D_ 128
#define T_ 2048
#define B_ 4
#define H_ 4
#define NB_ 2

// ===========================================================================
// Fragment-packed layouts (bf16, all frag loads are `base + lane*8`, 1KB):
//  wp[(j*NB+i)*32 + nt*4 + ks][lane][e]  = W[k=ks*32+(lane>>4)*8+e][n=nt*16+(lane&15)]
//  hp[(row>>4)*4 + ks][lane][e]          = A[row16+(lane&15)][ks*32+(lane>>4)*8+e]
//  cp[(qrow>>4)*4 + h][lane][e]          = ctx[...same A-frag pattern...]
//  qp[((b*64+qt)*4+h)*2+fs][lane][e]     = Q[b,qt*32+(lane&31)][h*32+fs*16+(lane>>5)*8+e]
//  kp[((b*4+h)*64+kt)*2+fs][lane][e]     = K[b,kt*32+(lane&31)][h*32+fs*16+(lane>>5)*8+e]
//  vp[((b*4+h)*64+tt)*2+fs][lane][e]     = V[b,tt*32+fs*16+(lane>>5)*8+e][h*32+(lane&31)]
// ===========================================================================

// ---------------------------------------------------------------------------
// Weight prep: fp32 [NB][128][128] -> frag-packed bf16 wp.
// ---------------------------------------------------------------------------
__global__ __launch_bounds__(256) void prep_weights(
    const float* __restrict__ Wq, const float* __restrict__ Wk,
    const float* __restrict__ Wv, const float* __restrict__ Wo,
    const float* __restrict__ W1, const float* __restrict__ W2,
    __bf16* __restrict__ wp)
{
  int tid = blockIdx.x * 256 + threadIdx.x;   // < 196608
  int e    = tid & 7;
  int lane = (tid >> 3) & 63;
  int ks   = (tid >> 9) & 3;
  int nt   = (tid >> 11) & 7;
  int i    = (tid >> 14) & (NB_ - 1);
  int j    = tid >> 15;
  int k = ks * 32 + (lane >> 4) * 8 + e;
  int n = nt * 16 + (lane & 15);
  const float* srcs[6] = {Wq, Wk, Wv, Wo, W1, W2};
  wp[tid] = (__bf16)srcs[j][i * 16384 + k * 128 + n];
}

// ---------------------------------------------------------------------------
// h0 = bf16(inputs + pos_encoding), written in hp (A-frag-packed) layout.
// ---------------------------------------------------------------------------
__global__ __launch_bounds__(256) void posadd(
    const float* __restrict__ x, __bf16* __restrict__ hp)
{
  int w = threadIdx.x >> 6, lane = threadIdx.x & 63;
  int row = blockIdx.x * 4 + w;
  int t = row & (T_ - 1);
  #pragma unroll
  for (int e = 0; e < 2; e++) {
    int c = lane * 2 + e;
    float arg = (float)t * exp2f(-0.20762050593045952f * (float)c);
    float pe = (c & 1) ? cosf(arg) : sinf(arg);
    float v = x[row * D_ + c] + pe;
    size_t idx = ((size_t)(row >> 4) * 4 + (c >> 5)) * 512 +
                 ((row & 15) + 16 * ((c >> 3) & 3)) * 8 + (c & 7);
    hp[idx] = (__bf16)v;
  }
}

// ---------------------------------------------------------------------------
// Fused LN + QKV (layer 0 only). 4 waves/block, wave w = head w.
// ---------------------------------------------------------------------------
__global__ __launch_bounds__(256) void lnqkv(
    const __bf16* __restrict__ hp, const __bf16* __restrict__ wpq,
    const __bf16* __restrict__ wpk, const __bf16* __restrict__ wpv,
    const float* __restrict__ bq, const float* __restrict__ bk,
    const float* __restrict__ bv, const float* __restrict__ g,
    const float* __restrict__ beta,
    __bf16* __restrict__ qp, __bf16* __restrict__ kp, __bf16* __restrict__ vp)
{
  int w = threadIdx.x >> 6, lane = threadIdx.x & 63;
  int m0 = blockIdx.x * 16;
  int lr = lane & 15, kg = lane >> 4;

  bf16x8 araw[4];
  #pragma unroll
  for (int ks = 0; ks < 4; ks++)
    araw[ks] = *(const bf16x8*)(hp + ((size_t)blockIdx.x * 4 + ks) * 512 + lane * 8);

  float s = 0.f, s2 = 0.f;
  #pragma unroll
  for (int ks = 0; ks < 4; ks++)
    #pragma unroll
    for (int e = 0; e < 8; e++) {
      float x = (float)araw[ks][e];
      s += x; s2 += x * x;
    }
  s += __shfl_xor(s, 16, 64);  s2 += __shfl_xor(s2, 16, 64);
  s += __shfl_xor(s, 32, 64);  s2 += __shfl_xor(s2, 32, 64);
  float mu = s * (1.f / D_);
  float var = s2 * (1.f / D_) - mu * mu;
  float rstd = rsqrtf(var + 1e-3f);

  bf16x8 af[4];
  #pragma unroll
  for (int ks = 0; ks < 4; ks++) {
    int c0 = ks * 32 + kg * 8;
    float4 g0 = *(const float4*)(g + c0), g1 = *(const float4*)(g + c0 + 4);
    float4 q0 = *(const float4*)(beta + c0), q1 = *(const float4*)(beta + c0 + 4);
    const float* gp[2] = {&g0.x, &g1.x};
    const float* bp[2] = {&q0.x, &q1.x};
    #pragma unroll
    for (int e = 0; e < 8; e++)
      af[ks][e] = (__bf16)(((float)araw[ks][e] - mu) * rstd * gp[e >> 2][e & 3] + bp[e >> 2][e & 3]);
  }

  #pragma unroll
  for (int i = 0; i < 2; i++) {
    int nt = w * 2 + i;
    const __bf16* wq = wpq + (size_t)(nt * 4) * 512 + lane * 8;
    const __bf16* wk = wpk + (size_t)(nt * 4) * 512 + lane * 8;
    const __bf16* wv = wpv + (size_t)(nt * 4) * 512 + lane * 8;
    f32x4 aq = {0, 0, 0, 0}, ak = {0, 0, 0, 0}, av = {0, 0, 0, 0};
    #pragma unroll
    for (int ks = 0; ks < 4; ks++) {
      aq = __builtin_amdgcn_mfma_f32_16x16x32_bf16(af[ks], *(const bf16x8*)(wq + ks * 512), aq, 0, 0, 0);
      ak = __builtin_amdgcn_mfma_f32_16x16x32_bf16(af[ks], *(const bf16x8*)(wk + ks * 512), ak, 0, 0, 0);
      av = __builtin_amdgcn_mfma_f32_16x16x32_bf16(af[ks], *(const bf16x8*)(wv + ks * 512), av, 0, 0, 0);
    }
    int col = nt * 16 + lr;
    float bqc = bq[col], bkc = bk[col], bvc = bv[col];
    int dk = i * 16 + lr;
    int hi8 = (lr >> 3) & 1;
    #pragma unroll
    for (int r = 0; r < 4; r++) {
      int row = m0 + kg * 4 + r;
      int bb = row >> 11, tt = row & (T_ - 1);
      size_t qidx = ((((size_t)(bb * 64 + (tt >> 5)) * 4 + w) * 2 + i) * 512) +
                    ((tt & 31) + 32 * hi8) * 8 + (lr & 7);
      qp[qidx] = (__bf16)(aq[r] + bqc);
      size_t kidx = ((((size_t)(bb * 4 + w) * 64 + (tt >> 5)) * 2 + i) * 512) +
                    ((tt & 31) + 32 * hi8) * 8 + (lr & 7);
      kp[kidx] = (__bf16)(ak[r] + bkc);
      size_t vidx = ((((size_t)(bb * 4 + w) * 64 + (tt >> 5)) * 2 + ((tt >> 4) & 1)) * 512) +
                    (dk + 32 * ((tt >> 3) & 1)) * 8 + (tt & 7);
      vp[vidx] = (__bf16)(av[r] + bvc);
    }
  }
}

// ---------------------------------------------------------------------------
// Flash attention v8: 32x32 swapped structure, frag-packed loads, 8-way KV
// split (8 waves/block, 512 threads, 8 iters each -> 2x TLP, half the serial
// chain of v7). Fixed-max softmax via C=-24, raw v_exp_f32, permlane32_swap.
// Merge 8 partials once via LDS. XCD swizzle via bh = blk&15.
// ---------------------------------------------------------------------------
__global__ __launch_bounds__(512) void attn8(
    const __bf16* __restrict__ qp, const __bf16* __restrict__ kp,
    const __bf16* __restrict__ vp, __bf16* __restrict__ cp)
{
  __shared__ float mbuf[7][64][17];

  int w = threadIdx.x >> 6, lane = threadIdx.x & 63;
  int bh = blockIdx.x & 15, qt = blockIdx.x >> 4;   // qt 0..63
  int b = bh >> 2, h = bh & 3;
  int lq = lane & 31, hi = lane >> 5;

  const float qscale = 0.17677669529663687f * 1.4426950408889634f;  // 1/sqrt(32)*log2e
  const __bf16* qbase = qp + (((size_t)(b * 64 + qt) * 4 + h) * 2) * 512 + lane * 8;
  bf16x8 qraw0 = *(const bf16x8*)(qbase);
  bf16x8 qraw1 = *(const bf16x8*)(qbase + 512);
  bf16x8 qf0, qf1;
  #pragma unroll
  for (int e = 0; e < 8; e++) {
    qf0[e] = (__bf16)((float)qraw0[e] * qscale);
    qf1[e] = (__bf16)((float)qraw1[e] * qscale);
  }

  const __bf16* kbase = kp + ((size_t)(b * 4 + h) * 64) * 1024 + lane * 8;
  const __bf16* vbase = vp + ((size_t)(b * 4 + h) * 64) * 1024 + lane * 8;

  f32x16 acc;
  #pragma unroll
  for (int r = 0; r < 16; r++) acc[r] = 0.f;
  float l = 0.f;

  int kt = w * 8;
  bf16x8 kf0 = *(const bf16x8*)(kbase + (size_t)kt * 1024);
  bf16x8 kf1 = *(const bf16x8*)(kbase + (size_t)kt * 1024 + 512);
  bf16x8 vf0 = *(const bf16x8*)(vbase + (size_t)kt * 1024);
  bf16x8 vf1 = *(const bf16x8*)(vbase + (size_t)kt * 1024 + 512);

  for (int it = 0; it < 8; it++) {
    __builtin_amdgcn_s_setprio(1);
    f32x16 s;
    #pragma unroll
    for (int r = 0; r < 16; r++) s[r] = -24.f;   // fixed-max bias via C-init
    s = __builtin_amdgcn_mfma_f32_32x32x16_bf16(kf0, qf0, s, 0, 0, 0);
    s = __builtin_amdgcn_mfma_f32_32x32x16_bf16(kf1, qf1, s, 0, 0, 0);
    __builtin_amdgcn_s_setprio(0);

    bf16x8 kn0, kn1, vn0, vn1;
    if (it < 7) {
      size_t nb = (size_t)(kt + 1) * 1024;
      kn0 = *(const bf16x8*)(kbase + nb);
      kn1 = *(const bf16x8*)(kbase + nb + 512);
      vn0 = *(const bf16x8*)(vbase + nb);
      vn1 = *(const bf16x8*)(vbase + nb + 512);
    }

    unsigned int aw[8];
    #pragma unroll
    for (int g = 0; g < 4; g++) {
      float p0 = __builtin_amdgcn_exp2f(s[g * 4 + 0]);
      float p1 = __builtin_amdgcn_exp2f(s[g * 4 + 1]);
      float p2 = __builtin_amdgcn_exp2f(s[g * 4 + 2]);
      float p3 = __builtin_amdgcn_exp2f(s[g * 4 + 3]);
      l += (p0 + p1) + (p2 + p3);
      unsigned int u01, u23;
      asm("v_cvt_pk_bf16_f32 %0, %1, %2" : "=v"(u01) : "v"(p0), "v"(p1));
      asm("v_cvt_pk_bf16_f32 %0, %1, %2" : "=v"(u23) : "v"(p2), "v"(p3));
      aw[g * 2] = u01; aw[g * 2 + 1] = u23;
    }
    unsigned int a0 = aw[0], a2 = aw[2];
    asm volatile("v_permlane32_swap_b32 %0, %1" : "+v"(a0), "+v"(a2));
    unsigned int a1 = aw[1], a3 = aw[3];
    asm volatile("v_permlane32_swap_b32 %0, %1" : "+v"(a1), "+v"(a3));
    bf16x8 pw0 = __builtin_bit_cast(bf16x8, (u32x4v){a0, a1, a2, a3});
    unsigned int a4 = aw[4], a6 = aw[6];
    asm volatile("v_permlane32_swap_b32 %0, %1" : "+v"(a4), "+v"(a6));
    unsigned int a5 = aw[5], a7 = aw[7];
    asm volatile("v_permlane32_swap_b32 %0, %1" : "+v"(a5), "+v"(a7));
    bf16x8 pw1 = __builtin_bit_cast(bf16x8, (u32x4v){a4, a5, a6, a7});

    __builtin_amdgcn_s_setprio(1);
    acc = __builtin_amdgcn_mfma_f32_32x32x16_bf16(vf0, pw0, acc, 0, 0, 0);
    acc = __builtin_amdgcn_mfma_f32_32x32x16_bf16(vf1, pw1, acc, 0, 0, 0);
    __builtin_amdgcn_s_setprio(0);

    kf0 = kn0; kf1 = kn1; vf0 = vn0; vf1 = vn1;
    kt += 1;
  }

  l += __shfl_xor(l, 32, 64);

  if (w > 0) {
    float* mb = &mbuf[w - 1][lane][0];
    #pragma unroll
    for (int r = 0; r < 16; r++) mb[r] = acc[r];
    mb[16] = l;
  }
  __syncthreads();
  if (w == 0) {
    #pragma unroll
    for (int w2_ = 0; w2_ < 7; w2_++) {
      const float* mb = &mbuf[w2_][lane][0];
      #pragma unroll
      for (int r = 0; r < 16; r++) acc[r] += mb[r];
      l += mb[16];
    }
    float inv = 1.f / l;
    __bf16* cbase = cp + ((size_t)(b * 128 + qt * 2 + (lq >> 4)) * 4 + h) * 512 + 4 * hi;
    #pragma unroll
    for (int g = 0; g < 4; g++) {
      bf16x4 o;
      #pragma unroll
      for (int j = 0; j < 4; j++) o[j] = (__bf16)(acc[g * 4 + j] * inv);
      *(bf16x4*)(cbase + ((lq & 15) + 16 * g) * 8) = o;
    }
  }
}

// ---------------------------------------------------------------------------
// Fused layer tail + next-layer QKV: Wo+bo -> LN -> W1+ReLU -> W2+res -> h,
// then LN(next) -> Q/K/V GEMMs -> packed stores. One dispatch, no hp trip.
// ---------------------------------------------------------------------------
__global__ __launch_bounds__(256) void wo_ffn_qkv(
    const __bf16* __restrict__ cp, const __bf16* __restrict__ wpo,
    const float* __restrict__ bo, const float* __restrict__ g1,
    const float* __restrict__ bt1, const __bf16* __restrict__ wp1,
    const float* __restrict__ b1, const __bf16* __restrict__ wp2,
    const float* __restrict__ b2,
    const float* __restrict__ gq, const float* __restrict__ btq,
    const __bf16* __restrict__ wpq, const __bf16* __restrict__ wpk,
    const __bf16* __restrict__ wpv,
    const float* __restrict__ bq, const float* __restrict__ bk,
    const float* __restrict__ bv,
    __bf16* __restrict__ qp, __bf16* __restrict__ kp, __bf16* __restrict__ vp)
{
  __shared__ __attribute__((aligned(16))) __bf16 tb0[16][128];
  __shared__ __attribute__((aligned(16))) __bf16 tb1[16][128];
  __shared__ float2 statb[16][4];

  int w = threadIdx.x >> 6, lane = threadIdx.x & 63;
  int m0 = blockIdx.x * 16;
  int lr = lane & 15, kg = lane >> 4;
  int swz = (lr & 7) << 3;

  bf16x8 af[4];
  #pragma unroll
  for (int ks = 0; ks < 4; ks++)
    af[ks] = *(const bf16x8*)(cp + ((size_t)blockIdx.x * 4 + ks) * 512 + lane * 8);

  // ---- Wo GEMM ----
  f32x4 acc[2] = {{0, 0, 0, 0}, {0, 0, 0, 0}};
  #pragma unroll
  for (int i = 0; i < 2; i++) {
    const __bf16* wrow = wpo + (size_t)((w * 2 + i) * 4) * 512 + lane * 8;
    #pragma unroll
    for (int ks = 0; ks < 4; ks++)
      acc[i] = __builtin_amdgcn_mfma_f32_16x16x32_bf16(af[ks], *(const bf16x8*)(wrow + ks * 512), acc[i], 0, 0, 0);
  }

  // ---- +bo, cross-wave LN ----
  float xv[2][4];
  float s[4] = {0, 0, 0, 0}, s2[4] = {0, 0, 0, 0};
  #pragma unroll
  for (int i = 0; i < 2; i++) {
    float bcol = bo[(w * 2 + i) * 16 + lr];
    #pragma unroll
    for (int r = 0; r < 4; r++) {
      float y = acc[i][r] + bcol;
      xv[i][r] = y; s[r] += y; s2[r] += y * y;
    }
  }
  #pragma unroll
  for (int r = 0; r < 4; r++)
    for (int mk = 1; mk < 16; mk <<= 1) {
      s[r] += __shfl_xor(s[r], mk, 64);
      s2[r] += __shfl_xor(s2[r], mk, 64);
    }
  if (lr == 0) {
    #pragma unroll
    for (int r = 0; r < 4; r++) statb[kg * 4 + r][w] = make_float2(s[r], s2[r]);
  }
  __syncthreads();
  float mu_[4], rstd_[4];
  #pragma unroll
  for (int r = 0; r < 4; r++) {
    int row = kg * 4 + r;
    float ss = 0.f, ss2 = 0.f;
    #pragma unroll
    for (int w2 = 0; w2 < 4; w2++) {
      float2 t = statb[row][w2];
      ss += t.x; ss2 += t.y;
    }
    mu_[r] = ss * (1.f / D_);
    float var = ss2 * (1.f / D_) - mu_[r] * mu_[r];
    rstd_[r] = rsqrtf(var + 1e-3f);
  }
  float hres[2][4];
  #pragma unroll
  for (int i = 0; i < 2; i++) {
    int col = (w * 2 + i) * 16 + lr;
    float gc = g1[col], bc = bt1[col];
    #pragma unroll
    for (int r = 0; r < 4; r++) {
      float y = (xv[i][r] - mu_[r]) * rstd_[r] * gc + bc;
      hres[i][r] = y;
      int row = kg * 4 + r;
      tb0[row][col ^ ((row & 7) << 3)] = (__bf16)y;
    }
  }
  __syncthreads();

  // ---- W1 + ReLU ----
  bf16x8 a2[4];
  #pragma unroll
  for (int ks = 0; ks < 4; ks++)
    a2[ks] = *(const bf16x8*)(&tb0[lr][(ks * 32 + kg * 8) ^ swz]);
  f32x4 acc2[2] = {{0, 0, 0, 0}, {0, 0, 0, 0}};
  #pragma unroll
  for (int i = 0; i < 2; i++) {
    const __bf16* wrow = wp1 + (size_t)((w * 2 + i) * 4) * 512 + lane * 8;
    #pragma unroll
    for (int ks = 0; ks < 4; ks++)
      acc2[i] = __builtin_amdgcn_mfma_f32_16x16x32_bf16(a2[ks], *(const bf16x8*)(wrow + ks * 512), acc2[i], 0, 0, 0);
  }
  #pragma unroll
  for (int i = 0; i < 2; i++) {
    float bcol = b1[(w * 2 + i) * 16 + lr];
    int col = (w * 2 + i) * 16 + lr;
    #pragma unroll
    for (int r = 0; r < 4; r++) {
      int row = kg * 4 + r;
      tb1[row][col ^ ((row & 7) << 3)] = (__bf16)fmaxf(acc2[i][r] + bcol, 0.f);
    }
  }
  __syncthreads();

  // ---- W2 + residual -> h ----
  bf16x8 a3[4];
  #pragma unroll
  for (int ks = 0; ks < 4; ks++)
    a3[ks] = *(const bf16x8*)(&tb1[lr][(ks * 32 + kg * 8) ^ swz]);
  f32x4 acc3[2] = {{0, 0, 0, 0}, {0, 0, 0, 0}};
  #pragma unroll
  for (int i = 0; i < 2; i++) {
    const __bf16* wrow = wp2 + (size_t)((w * 2 + i) * 4) * 512 + lane * 8;
    #pragma unroll
    for (int ks = 0; ks < 4; ks++)
      acc3[i] = __builtin_amdgcn_mfma_f32_16x16x32_bf16(a3[ks], *(const bf16x8*)(wrow + ks * 512), acc3[i], 0, 0, 0);
  }

  // ---- h -> tb0 (transpose for A-frags); safe: tb0's last read was a2 ----
  #pragma unroll
  for (int i = 0; i < 2; i++) {
    int col = (w * 2 + i) * 16 + lr;
    float bcol = b2[col];
    #pragma unroll
    for (int r = 0; r < 4; r++) {
      int row = kg * 4 + r;
      tb0[row][col ^ ((row & 7) << 3)] = (__bf16)(acc3[i][r] + bcol + hres[i][r]);
    }
  }
  __syncthreads();

  // ---- next-layer LN (in-register, row = lr) ----
  bf16x8 araw[4];
  #pragma unroll
  for (int ks = 0; ks < 4; ks++)
    araw[ks] = *(const bf16x8*)(&tb0[lr][(ks * 32 + kg * 8) ^ swz]);
  float t = 0.f, t2 = 0.f;
  #pragma unroll
  for (int ks = 0; ks < 4; ks++)
    #pragma unroll
    for (int e = 0; e < 8; e++) {
      float x = (float)araw[ks][e];
      t += x; t2 += x * x;
    }
  t += __shfl_xor(t, 16, 64);  t2 += __shfl_xor(t2, 16, 64);
  t += __shfl_xor(t, 32, 64);  t2 += __shfl_xor(t2, 32, 64);
  float mu = t * (1.f / D_);
  float var = t2 * (1.f / D_) - mu * mu;
  float rstd = rsqrtf(var + 1e-3f);

  bf16x8 af2[4];
  #pragma unroll
  for (int ks = 0; ks < 4; ks++) {
    int c0 = ks * 32 + kg * 8;
    float4 g0 = *(const float4*)(gq + c0), g1v = *(const float4*)(gq + c0 + 4);
    float4 q0 = *(const float4*)(btq + c0), q1 = *(const float4*)(btq + c0 + 4);
    const float* gp[2] = {&g0.x, &g1v.x};
    const float* bp[2] = {&q0.x, &q1.x};
    #pragma unroll
    for (int e = 0; e < 8; e++)
      af2[ks][e] = (__bf16)(((float)araw[ks][e] - mu) * rstd * gp[e >> 2][e & 3] + bp[e >> 2][e & 3]);
  }

  // ---- QKV GEMMs + packed stores (wave w = head w) ----
  #pragma unroll
  for (int i = 0; i < 2; i++) {
    int nt = w * 2 + i;
    const __bf16* wq = wpq + (size_t)(nt * 4) * 512 + lane * 8;
    const __bf16* wk = wpk + (size_t)(nt * 4) * 512 + lane * 8;
    const __bf16* wv = wpv + (size_t)(nt * 4) * 512 + lane * 8;
    f32x4 aq = {0, 0, 0, 0}, ak = {0, 0, 0, 0}, av = {0, 0, 0, 0};
    #pragma unroll
    for (int ks = 0; ks < 4; ks++) {
      aq = __builtin_amdgcn_mfma_f32_16x16x32_bf16(af2[ks], *(const bf16x8*)(wq + ks * 512), aq, 0, 0, 0);
      ak = __builtin_amdgcn_mfma_f32_16x16x32_bf16(af2[ks], *(const bf16x8*)(wk + ks * 512), ak, 0, 0, 0);
      av = __builtin_amdgcn_mfma_f32_16x16x32_bf16(af2[ks], *(const bf16x8*)(wv + ks * 512), av, 0, 0, 0);
    }
    int col = nt * 16 + lr;
    float bqc = bq[col], bkc = bk[col], bvc = bv[col];
    int dk = i * 16 + lr;
    int hi8 = (lr >> 3) & 1;
    #pragma unroll
    for (int r = 0; r < 4; r++) {
      int row = m0 + kg * 4 + r;
      int bb = row >> 11, tt = row & (T_ - 1);
      size_t qidx = ((((size_t)(bb * 64 + (tt >> 5)) * 4 + w) * 2 + i) * 512) +
                    ((tt & 31) + 32 * hi8) * 8 + (lr & 7);
      qp[qidx] = (__bf16)(aq[r] + bqc);
      size_t kidx = ((((size_t)(bb * 4 + w) * 64 + (tt >> 5)) * 2 + i) * 512) +
                    ((tt & 31) + 32 * hi8) * 8 + (lr & 7);
      kp[kidx] = (__bf16)(ak[r] + bkc);
      size_t vidx = ((((size_t)(bb * 4 + w) * 64 + (tt >> 5)) * 2 + ((tt >> 4) & 1)) * 512) +
                    (dk + 32 * ((tt >> 3) & 1)) * 8 + (tt & 7);
      vp[vidx] = (__bf16)(av[r] + bvc);
    }
  }
}

// ---------------------------------------------------------------------------
// Final layer tail: Wo+bo -> LN -> W1+ReLU -> W2+res -> final LN -> fp32 out.
// ---------------------------------------------------------------------------
__global__ __launch_bounds__(256) void wo_ffn_last(
    const __bf16* __restrict__ cp, const __bf16* __restrict__ wpo,
    const float* __restrict__ bo, const float* __restrict__ g1,
    const float* __restrict__ bt1, const __bf16* __restrict__ wp1,
    const float* __restrict__ b1, const __bf16* __restrict__ wp2,
    const float* __restrict__ b2, const float* __restrict__ g2,
    const float* __restrict__ bt2, float* __restrict__ outf)
{
  __shared__ __attribute__((aligned(16))) __bf16 tb0[16][128];
  __shared__ __attribute__((aligned(16))) __bf16 tb1[16][128];
  __shared__ float2 statb[16][4];

  int w = threadIdx.x >> 6, lane = threadIdx.x & 63;
  int m0 = blockIdx.x * 16;
  int lr = lane & 15, kg = lane >> 4;
  int swz = (lr & 7) << 3;

  bf16x8 af[4];
  #pragma unroll
  for (int ks = 0; ks < 4; ks++)
    af[ks] = *(const bf16x8*)(cp + ((size_t)blockIdx.x * 4 + ks) * 512 + lane * 8);

  f32x4 acc[2] = {{0, 0, 0, 0}, {0, 0, 0, 0}};
  #pragma unroll
  for (int i = 0; i < 2; i++) {
    const __bf16* wrow = wpo + (size_t)((w * 2 + i) * 4) * 512 + lane * 8;
    #pragma unroll
    for (int ks = 0; ks < 4; ks++)
      acc[i] = __builtin_amdgcn_mfma_f32_16x16x32_bf16(af[ks], *(const bf16x8*)(wrow + ks * 512), acc[i], 0, 0, 0);
  }

  float xv[2][4];
  float s[4] = {0, 0, 0, 0}, s2[4] = {0, 0, 0, 0};
  #pragma unroll
  for (int i = 0; i < 2; i++) {
    float bcol = bo[(w * 2 + i) * 16 + lr];
    #pragma unroll
    for (int r = 0; r < 4; r++) {
      float y = acc[i][r] + bcol;
      xv[i][r] = y; s[r] += y; s2[r] += y * y;
    }
  }
  #pragma unroll
  for (int r = 0; r < 4; r++)
    for (int mk = 1; mk < 16; mk <<= 1) {
      s[r] += __shfl_xor(s[r], mk, 64);
      s2[r] += __shfl_xor(s2[r], mk, 64);
    }
  if (lr == 0) {
    #pragma unroll
    for (int r = 0; r < 4; r++) statb[kg * 4 + r][w] = make_float2(s[r], s2[r]);
  }
  __syncthreads();
  float mu_[4], rstd_[4];
  #pragma unroll
  for (int r = 0; r < 4; r++) {
    int row = kg * 4 + r;
    float ss = 0.f, ss2 = 0.f;
    #pragma unroll
    for (int w2 = 0; w2 < 4; w2++) {
      float2 t = statb[row][w2];
      ss += t.x; ss2 += t.y;
    }
    mu_[r] = ss * (1.f / D_);
    float var = ss2 * (1.f / D_) - mu_[r] * mu_[r];
    rstd_[r] = rsqrtf(var + 1e-3f);
  }
  float hres[2][4];
  #pragma unroll
  for (int i = 0; i < 2; i++) {
    int col = (w * 2 + i) * 16 + lr;
    float gc = g1[col], bc = bt1[col];
    #pragma unroll
    for (int r = 0; r < 4; r++) {
      float y = (xv[i][r] - mu_[r]) * rstd_[r] * gc + bc;
      hres[i][r] = y;
      int row = kg * 4 + r;
      tb0[row][col ^ ((row & 7) << 3)] = (__bf16)y;
    }
  }
  __syncthreads();

  bf16x8 a2[4];
  #pragma unroll
  for (int ks = 0; ks < 4; ks++)
    a2[ks] = *(const bf16x8*)(&tb0[lr][(ks * 32 + kg * 8) ^ swz]);
  f32x4 acc2[2] = {{0, 0, 0, 0}, {0, 0, 0, 0}};
  #pragma unroll
  for (int i = 0; i < 2; i++) {
    const __bf16* wrow = wp1 + (size_t)((w * 2 + i) * 4) * 512 + lane * 8;
    #pragma unroll
    for (int ks = 0; ks < 4; ks++)
      acc2[i] = __builtin_amdgcn_mfma_f32_16x16x32_bf16(a2[ks], *(const bf16x8*)(wrow + ks * 512), acc2[i], 0, 0, 0);
  }
  #pragma unroll
  for (int i = 0; i < 2; i++) {
    float bcol = b1[(w * 2 + i) * 16 + lr];
    int col = (w * 2 + i) * 16 + lr;
    #pragma unroll
    for (int r = 0; r < 4; r++) {
      int row = kg * 4 + r;
      tb1[row][col ^ ((row & 7) << 3)] = (__bf16)fmaxf(acc2[i][r] + bcol, 0.f);
    }
  }
  __syncthreads();

  bf16x8 a3[4];
  #pragma unroll
  for (int ks = 0; ks < 4; ks++)
    a3[ks] = *(const bf16x8*)(&tb1[lr][(ks * 32 + kg * 8) ^ swz]);
  f32x4 acc3[2] = {{0, 0, 0, 0}, {0, 0, 0, 0}};
  #pragma unroll
  for (int i = 0; i < 2; i++) {
    const __bf16* wrow = wp2 + (size_t)((w * 2 + i) * 4) * 512 + lane * 8;
    #pragma unroll
    for (int ks = 0; ks < 4; ks++)
      acc3[i] = __builtin_amdgcn_mfma_f32_16x16x32_bf16(a3[ks], *(const bf16x8*)(wrow + ks * 512), acc3[i], 0, 0, 0);
  }

  float yv[2][4];
  float t[4] = {0, 0, 0, 0}, t2[4] = {0, 0, 0, 0};
  #pragma unroll
  for (int i = 0; i < 2; i++) {
    float bcol = b2[(w * 2 + i) * 16 + lr];
    #pragma unroll
    for (int r = 0; r < 4; r++) {
      float y = acc3[i][r] + bcol + hres[i][r];
      yv[i][r] = y; t[r] += y; t2[r] += y * y;
    }
  }
  #pragma unroll
  for (int r = 0; r < 4; r++)
    for (int mk = 1; mk < 16; mk <<= 1) {
      t[r] += __shfl_xor(t[r], mk, 64);
      t2[r] += __shfl_xor(t2[r], mk, 64);
    }
  __syncthreads();
  if (lr == 0) {
    #pragma unroll
    for (int r = 0; r < 4; r++) statb[kg * 4 + r][w] = make_float2(t[r], t2[r]);
  }
  __syncthreads();
  #pragma unroll
  for (int r = 0; r < 4; r++) {
    int row = kg * 4 + r;
    float ss = 0.f, ss2 = 0.f;
    #pragma unroll
    for (int w2 = 0; w2 < 4; w2++) {
      float2 tt = statb[row][w2];
      ss += tt.x; ss2 += tt.y;
    }
    float mu = ss * (1.f / D_);
    float var = ss2 * (1.f / D_) - mu * mu;
    float rstd = rsqrtf(var + 1e-3f);
    #pragma unroll
    for (int i = 0; i < 2; i++) {
      int col = (w * 2 + i) * 16 + lr;
      outf[(size_t)(m0 + row) * D_ + col] =
          (yv[i][r] - mu) * rstd * g2[col] + bt2[col];
    }
  }
}

// ---------------------------------------------------------------------------
extern "C" void kernel_launch(void* const* d_in, const int* in_sizes, int n_in,
                              void* d_out, int out_size, void* d_ws, size_t ws_size,
                              hipStream_t stream)
{
  const float* inputs = (const float*)d_in[0];
  const float* Wq = (const float*)d_in[1];
  const float* bq = (const float*)d_in[2];
  const float* Wk = (const float*)d_in[3];
  const float* bk = (const float*)d_in[4];
  const float* Wv = (const float*)d_in[5];
  const float* bv = (const float*)d_in[6];
  const float* Wo = (const float*)d_in[7];
  const float* bo = (const float*)d_in[8];
  const float* W1 = (const float*)d_in[9];
  const float* b1 = (const float*)d_in[10];
  const float* W2 = (const float*)d_in[11];
  const float* b2 = (const float*)d_in[12];
  const float* ln_g = (const float*)d_in[13];
  const float* ln_b = (const float*)d_in[14];
  float* out = (float*)d_out;

  char* ws = (char*)d_ws;
  size_t off = 0;
  auto alloc = [&](size_t bytes) {
    void* p = ws + off;
    off = (off + bytes + 255) & ~(size_t)255;
    return p;
  };
  const size_t ACT = (size_t)8192 * 128 * sizeof(__bf16);  // 2 MB
  __bf16* wp = (__bf16*)alloc((size_t)6 * NB_ * 16384 * sizeof(__bf16));
  __bf16* hp = (__bf16*)alloc(ACT);
  __bf16* qp = (__bf16*)alloc(ACT);
  __bf16* kp = (__bf16*)alloc(ACT);
  __bf16* vp = (__bf16*)alloc(ACT);
  __bf16* cb = (__bf16*)alloc(ACT);

  prep_weights<<<768, 256, 0, stream>>>(Wq, Wk, Wv, Wo, W1, W2, wp);
  posadd<<<2048, 256, 0, stream>>>(inputs, hp);

  const __bf16* wpq0 = wp + (size_t)(0 * NB_ + 0) * 16384;
  const __bf16* wpk0 = wp + (size_t)(1 * NB_ + 0) * 16384;
  const __bf16* wpv0 = wp + (size_t)(2 * NB_ + 0) * 16384;
  const __bf16* wpo0 = wp + (size_t)(3 * NB_ + 0) * 16384;
  const __bf16* wp10 = wp + (size_t)(4 * NB_ + 0) * 16384;
  const __bf16* wp20 = wp + (size_t)(5 * NB_ + 0) * 16384;
  const __bf16* wpq1 = wp + (size_t)(0 * NB_ + 1) * 16384;
  const __bf16* wpk1 = wp + (size_t)(1 * NB_ + 1) * 16384;
  const __bf16* wpv1 = wp + (size_t)(2 * NB_ + 1) * 16384;
  const __bf16* wpo1 = wp + (size_t)(3 * NB_ + 1) * 16384;
  const __bf16* wp11 = wp + (size_t)(4 * NB_ + 1) * 16384;
  const __bf16* wp21 = wp + (size_t)(5 * NB_ + 1) * 16384;

  // layer 0
  lnqkv<<<512, 256, 0, stream>>>(hp, wpq0, wpk0, wpv0, bq, bk, bv,
                                 ln_g, ln_b, qp, kp, vp);
  attn8<<<1024, 512, 0, stream>>>(qp, kp, vp, cb);
  // tail of layer 0 fused with layer 1's LN+QKV
  wo_ffn_qkv<<<512, 256, 0, stream>>>(cb, wpo0, bo,
                                      ln_g + 128, ln_b + 128, wp10, b1, wp20, b2,
                                      ln_g + 2 * 128, ln_b + 2 * 128,
                                      wpq1, wpk1, wpv1,
                                      bq + 128, bk + 128, bv + 128,
                                      qp, kp, vp);
  // layer 1
  attn8<<<1024, 512, 0, stream>>>(qp, kp, vp, cb);
  wo_ffn_last<<<512, 256, 0, stream>>>(cb, wpo1, bo + 128,
                                       ln_g + 3 * 128, ln_b + 3 * 128,
                                       wp11, b1 + 128, wp21, b2 + 128,
                                       ln_g + 3 * 128, ln_b + 3 * 128, out);
}